// Round 2
// baseline (1524.425 us; speedup 1.0000x reference)
//
#include <hip/hip_runtime.h>

#define NN     50000
#define NE     20000
#define NNZV   800000
#define FD     256
#define EPSV   1e-5f
#define MPAD   20032     // NE rounded up to 64 for GEMM tiling
#define E2N_GROUP 16     // nodes per wave in e2n gather

typedef __attribute__((ext_vector_type(8))) __bf16 bf16x8;
typedef __attribute__((ext_vector_type(4))) __bf16 bf16x4;
typedef __attribute__((ext_vector_type(4))) float f32x4;

__device__ __forceinline__ float b2f(unsigned short u) {
  union { unsigned int i; float f; } z; z.i = ((unsigned)u) << 16; return z.f;
}

// ---- CSR construction -------------------------------------------------------

__global__ void hg_hist(const int* __restrict__ nidx, const int* __restrict__ eidx,
                        const float* __restrict__ wedge,
                        int* __restrict__ cnt_e, int* __restrict__ cnt_n,
                        float* __restrict__ Dacc) {
  int i = blockIdx.x * 256 + threadIdx.x;
  if (i >= NNZV) return;
  int e = eidx[i];
  int n = nidx[i];
  atomicAdd(&cnt_e[e], 1);
  atomicAdd(&cnt_n[n], 1);
  atomicAdd(&Dacc[n], wedge[e]);
}

__global__ void hg_exscan(const int* __restrict__ cnt, int n, int* __restrict__ off) {
  __shared__ int lds[1024];
  int t = threadIdx.x;
  int chunk = (n + 1023) >> 10;
  long lo = (long)t * chunk;
  long hi = lo + chunk;
  if (lo > n) lo = n;
  if (hi > n) hi = n;
  int s = 0;
  for (long i = lo; i < hi; ++i) s += cnt[i];
  lds[t] = s;
  for (int d = 1; d < 1024; d <<= 1) {
    __syncthreads();
    int u = (t >= d) ? lds[t - d] : 0;
    int v = lds[t];
    __syncthreads();
    lds[t] = u + v;
  }
  __syncthreads();
  int run = (t == 0) ? 0 : lds[t - 1];
  for (long i = lo; i < hi; ++i) { off[i] = run; run += cnt[i]; }
  if (t == 1023) off[n] = lds[1023];
}

__global__ void hg_scatter(const int* __restrict__ nidx, const int* __restrict__ eidx,
                           const int* __restrict__ off_e, const int* __restrict__ off_n,
                           int* __restrict__ cur_e, int* __restrict__ cur_n,
                           int* __restrict__ mem_e, int* __restrict__ mem_n) {
  int i = blockIdx.x * 256 + threadIdx.x;
  if (i >= NNZV) return;
  int n = nidx[i];
  int e = eidx[i];
  int pe = atomicAdd(&cur_e[e], 1);
  mem_e[off_e[e] + pe] = n;
  int pn = atomicAdd(&cur_n[n], 1);
  mem_n[off_n[n] + pn] = e;
}

__global__ void hg_inv(const int* __restrict__ cnt_e, const float* __restrict__ Dacc,
                       float* __restrict__ Binv, float* __restrict__ Dinv) {
  int i = blockIdx.x * 256 + threadIdx.x;
  if (i < NE) Binv[i] = cnt_e[i] ? 1.0f / (float)cnt_e[i] : 0.0f;
  if (i < NN) {
    float d = Dacc[i];
    Dinv[i] = (d != 0.0f) ? 1.0f / d : 0.0f;
  }
}

// ---- weights to bf16, transposed (Wt[n][k] = W[k][n]) -----------------------

__global__ void hg_wconv(const float* __restrict__ W1, const float* __restrict__ W2,
                         __bf16* __restrict__ Wt1, __bf16* __restrict__ Wt2) {
  int id = blockIdx.x * 256 + threadIdx.x;  // 65536 total
  int n = id >> 8;
  int k = id & 255;
  Wt1[n * FD + k] = (__bf16)W1[k * FD + n];
  Wt2[n * FD + k] = (__bf16)W2[k * FD + n];
}

// ---- x (f32) -> bf16 --------------------------------------------------------

__global__ void hg_x2bf(const float* __restrict__ X, __bf16* __restrict__ Xbf) {
  int idx = blockIdx.x * 256 + threadIdx.x;   // over NN*FD/4
  if (idx >= NN * FD / 4) return;
  float4 v = ((const float4*)X)[idx];
  bf16x4 o = {(__bf16)v.x, (__bf16)v.y, (__bf16)v.z, (__bf16)v.w};
  ((bf16x4*)Xbf)[idx] = o;
}

// ---- node -> edge aggregation (wave per edge, 4 cols/lane, bf16 rows) -------
// APPLY=1: apply previous layer's BN scale/shift + ReLU to each gathered elem.

template<int APPLY>
__global__ void hg_agg_n2e_bf(const __bf16* __restrict__ Xbf, const int* __restrict__ off_e,
                              const int* __restrict__ mem_e, const float* __restrict__ Binv,
                              const float* __restrict__ scale, const float* __restrict__ shift,
                              __bf16* __restrict__ Ebf) {
  int wid = blockIdx.x * 4 + (threadIdx.x >> 6);   // edge id
  if (wid >= NE) return;
  int lane = threadIdx.x & 63;
  int c = lane * 4;
  float sc0 = 0.f, sc1 = 0.f, sc2 = 0.f, sc3 = 0.f;
  float sh0 = 0.f, sh1 = 0.f, sh2 = 0.f, sh3 = 0.f;
  if (APPLY) {
    float4 s4 = *(const float4*)(scale + c);
    float4 h4 = *(const float4*)(shift + c);
    sc0 = s4.x; sc1 = s4.y; sc2 = s4.z; sc3 = s4.w;
    sh0 = h4.x; sh1 = h4.y; sh2 = h4.z; sh3 = h4.w;
  }
  int lo = off_e[wid], hi = off_e[wid + 1];
  float a0 = 0.f, a1 = 0.f, a2 = 0.f, a3 = 0.f;
  const unsigned short* Xu = (const unsigned short*)Xbf;
  for (int m = lo; m < hi; ++m) {
    int node = mem_e[m];
    ushort4 v = *(const ushort4*)(Xu + (size_t)node * FD + c);
    float f0 = b2f(v.x), f1 = b2f(v.y), f2 = b2f(v.z), f3 = b2f(v.w);
    if (APPLY) {
      f0 = fmaxf(fmaf(f0, sc0, sh0), 0.f);
      f1 = fmaxf(fmaf(f1, sc1, sh1), 0.f);
      f2 = fmaxf(fmaf(f2, sc2, sh2), 0.f);
      f3 = fmaxf(fmaf(f3, sc3, sh3), 0.f);
    }
    a0 += f0; a1 += f1; a2 += f2; a3 += f3;
  }
  float bi = Binv[wid];
  bf16x4 o = {(__bf16)(a0 * bi), (__bf16)(a1 * bi), (__bf16)(a2 * bi), (__bf16)(a3 * bi)};
  *(bf16x4*)(Ebf + (size_t)wid * FD + c) = o;
}

// ---- GEMM: C[M x 256] = A[M x 256] @ Bt^T, bf16 MFMA, bf16 out --------------

__global__ void hg_gemm(const __bf16* __restrict__ A, const __bf16* __restrict__ Bt,
                        __bf16* __restrict__ C, int Mrows) {
  int tid = threadIdx.x;
  int w = tid >> 6;
  int l = tid & 63;
  int m0 = blockIdx.x * 64 + w * 16;
  int n0 = blockIdx.y * 16;
  int kbase = (l >> 4) * 8;
  const bf16x8* Ap = (const bf16x8*)(A + (size_t)(m0 + (l & 15)) * FD + kbase);
  const bf16x8* Bp = (const bf16x8*)(Bt + (size_t)(n0 + (l & 15)) * FD + kbase);
  f32x4 acc = {0.f, 0.f, 0.f, 0.f};
#pragma unroll
  for (int ks = 0; ks < 8; ++ks) {
    bf16x8 a = Ap[ks * 4];   // +32 bf16 per k-step
    bf16x8 b = Bp[ks * 4];
    acc = __builtin_amdgcn_mfma_f32_16x16x32_bf16(a, b, acc, 0, 0, 0);
  }
  int crow = m0 + (l >> 4) * 4;
  int ccol = n0 + (l & 15);
#pragma unroll
  for (int r = 0; r < 4; ++r) {
    int rr = crow + r;
    if (rr < Mrows) C[(size_t)rr * FD + ccol] = (__bf16)acc[r];
  }
}

// ---- edge -> node aggregation + bias + BN partial stats (bf16 in/out) -------
// Wave handles E2N_GROUP consecutive nodes; lane owns 4 columns.

__global__ void hg_agg_e2n_bf(const __bf16* __restrict__ eWbf, const int* __restrict__ off_n,
                              const int* __restrict__ mem_n, const float* __restrict__ Dinv,
                              const float* __restrict__ bias,
                              __bf16* __restrict__ Outbf, float* __restrict__ stats) {
  int wid = blockIdx.x * 4 + (threadIdx.x >> 6);
  int nbase = wid * E2N_GROUP;
  if (nbase >= NN) return;
  int lane = threadIdx.x & 63;
  int c = lane * 4;
  float4 b4 = *(const float4*)(bias + c);
  const unsigned short* eWu = (const unsigned short*)eWbf;
  float s0 = 0.f, s1 = 0.f, s2 = 0.f, s3 = 0.f;
  float q0 = 0.f, q1 = 0.f, q2 = 0.f, q3 = 0.f;
  for (int i = 0; i < E2N_GROUP; ++i) {
    int node = nbase + i;
    if (node >= NN) break;
    int lo = off_n[node], hi = off_n[node + 1];
    float a0 = 0.f, a1 = 0.f, a2 = 0.f, a3 = 0.f;
    for (int m = lo; m < hi; ++m) {
      int e = mem_n[m];
      ushort4 v = *(const ushort4*)(eWu + (size_t)e * FD + c);
      a0 += b2f(v.x); a1 += b2f(v.y); a2 += b2f(v.z); a3 += b2f(v.w);
    }
    float di = Dinv[node];
    float v0 = fmaf(a0, di, b4.x);
    float v1 = fmaf(a1, di, b4.y);
    float v2 = fmaf(a2, di, b4.z);
    float v3 = fmaf(a3, di, b4.w);
    bf16x4 o = {(__bf16)v0, (__bf16)v1, (__bf16)v2, (__bf16)v3};
    *(bf16x4*)(Outbf + (size_t)node * FD + c) = o;
    s0 += v0; s1 += v1; s2 += v2; s3 += v3;
    q0 = fmaf(v0, v0, q0); q1 = fmaf(v1, v1, q1);
    q2 = fmaf(v2, v2, q2); q3 = fmaf(v3, v3, q3);
  }
  atomicAdd(&stats[c + 0], s0);
  atomicAdd(&stats[c + 1], s1);
  atomicAdd(&stats[c + 2], s2);
  atomicAdd(&stats[c + 3], s3);
  atomicAdd(&stats[FD + c + 0], q0);
  atomicAdd(&stats[FD + c + 1], q1);
  atomicAdd(&stats[FD + c + 2], q2);
  atomicAdd(&stats[FD + c + 3], q3);
}

// ---- BN finalize + final fused apply/ReLU -----------------------------------

__global__ void hg_bn_finalize(const float* __restrict__ stats, const float* __restrict__ g,
                               const float* __restrict__ be,
                               float* __restrict__ scale, float* __restrict__ shift) {
  int c = threadIdx.x;
  float mu = stats[c] * (1.0f / NN);
  float var = stats[FD + c] * (1.0f / NN) - mu * mu;
  float sc = g[c] * rsqrtf(var + EPSV);
  scale[c] = sc;
  shift[c] = fmaf(-mu, sc, be[c]);
}

__global__ void hg_apply_bf(const __bf16* __restrict__ Outbf, const float* __restrict__ scale,
                            const float* __restrict__ shift, float* __restrict__ H) {
  int idx = blockIdx.x * 256 + threadIdx.x;   // over NN*FD/8
  if (idx >= NN * FD / 8) return;
  ushort4 v0 = ((const ushort4*)Outbf)[idx * 2 + 0];
  ushort4 v1 = ((const ushort4*)Outbf)[idx * 2 + 1];
  int c = (idx & (FD / 8 - 1)) * 8;
  float4 sa = *(const float4*)(scale + c);
  float4 sb = *(const float4*)(scale + c + 4);
  float4 ha = *(const float4*)(shift + c);
  float4 hb = *(const float4*)(shift + c + 4);
  float4 o0, o1;
  o0.x = fmaxf(fmaf(b2f(v0.x), sa.x, ha.x), 0.f);
  o0.y = fmaxf(fmaf(b2f(v0.y), sa.y, ha.y), 0.f);
  o0.z = fmaxf(fmaf(b2f(v0.z), sa.z, ha.z), 0.f);
  o0.w = fmaxf(fmaf(b2f(v0.w), sa.w, ha.w), 0.f);
  o1.x = fmaxf(fmaf(b2f(v1.x), sb.x, hb.x), 0.f);
  o1.y = fmaxf(fmaf(b2f(v1.y), sb.y, hb.y), 0.f);
  o1.z = fmaxf(fmaf(b2f(v1.z), sb.z, hb.z), 0.f);
  o1.w = fmaxf(fmaf(b2f(v1.w), sb.w, hb.w), 0.f);
  ((float4*)H)[idx * 2 + 0] = o0;
  ((float4*)H)[idx * 2 + 1] = o1;
}

// ---- launch -----------------------------------------------------------------

extern "C" void kernel_launch(void* const* d_in, const int* in_sizes, int n_in,
                              void* d_out, int out_size, void* d_ws, size_t ws_size,
                              hipStream_t stream) {
  const float* x    = (const float*)d_in[0];
  const int*   hei  = (const int*)d_in[1];
  const int*   nidx = hei;               // hyperedge_index[0]
  const int*   eidx = hei + NNZV;        // hyperedge_index[1]
  const float* wedge = (const float*)d_in[2];
  const float* W1  = (const float*)d_in[3];
  const float* b1  = (const float*)d_in[4];
  const float* g1  = (const float*)d_in[5];
  const float* be1 = (const float*)d_in[6];
  const float* W2  = (const float*)d_in[7];
  const float* b2  = (const float*)d_in[8];
  const float* g2  = (const float*)d_in[9];
  const float* be2 = (const float*)d_in[10];
  float* out = (float*)d_out;

  char* base = (char*)d_ws;
  size_t cur = 0;
  auto alloc = [&](size_t bytes) -> void* {
    void* p = base + cur;
    cur += (bytes + 255) & ~(size_t)255;
    return p;
  };
  // zero-initialized group (single memset over the span)
  int*   cnt_e = (int*)alloc(NE * 4);
  int*   cnt_n = (int*)alloc(NN * 4);
  int*   cur_e = (int*)alloc(NE * 4);
  int*   cur_n = (int*)alloc(NN * 4);
  float* Dacc  = (float*)alloc(NN * 4);
  size_t zero_span = cur;
  // rest
  int*   off_e = (int*)alloc((NE + 1) * 4);
  int*   off_n = (int*)alloc((NN + 1) * 4);
  int*   mem_e = (int*)alloc((size_t)NNZV * 4);
  int*   mem_n = (int*)alloc((size_t)NNZV * 4);
  float* Dinv  = (float*)alloc(NN * 4);
  float* Binv  = (float*)alloc(NE * 4);
  __bf16* Wt1  = (__bf16*)alloc(FD * FD * 2);
  __bf16* Wt2  = (__bf16*)alloc(FD * FD * 2);
  __bf16* Xbf  = (__bf16*)alloc((size_t)NN * FD * 2);
  __bf16* Ebf  = (__bf16*)alloc((size_t)MPAD * FD * 2);
  __bf16* eWbf = (__bf16*)alloc((size_t)MPAD * FD * 2);
  __bf16* Outbf = (__bf16*)alloc((size_t)NN * FD * 2);
  float* stats = (float*)alloc(2 * FD * 4);
  float* scale1 = (float*)alloc(FD * 4);
  float* shift1 = (float*)alloc(FD * 4);
  float* scale2 = (float*)alloc(FD * 4);
  float* shift2 = (float*)alloc(FD * 4);
  if (cur > ws_size) return;

  hipMemsetAsync(base, 0, zero_span, stream);

  hg_hist<<<(NNZV + 255) / 256, 256, 0, stream>>>(nidx, eidx, wedge, cnt_e, cnt_n, Dacc);
  hg_exscan<<<1, 1024, 0, stream>>>(cnt_e, NE, off_e);
  hg_exscan<<<1, 1024, 0, stream>>>(cnt_n, NN, off_n);
  hg_scatter<<<(NNZV + 255) / 256, 256, 0, stream>>>(nidx, eidx, off_e, off_n,
                                                     cur_e, cur_n, mem_e, mem_n);
  hg_inv<<<(NN + 255) / 256, 256, 0, stream>>>(cnt_e, Dacc, Binv, Dinv);
  hg_wconv<<<FD, 256, 0, stream>>>(W1, W2, Wt1, Wt2);
  hg_x2bf<<<(NN * FD / 4 + 255) / 256, 256, 0, stream>>>(x, Xbf);

  const int N2E_BLOCKS = (NE + 3) / 4;
  const int E2N_BLOCKS = ((NN + E2N_GROUP - 1) / E2N_GROUP + 3) / 4;

  // ---- layer 1
  hg_agg_n2e_bf<0><<<N2E_BLOCKS, 256, 0, stream>>>(Xbf, off_e, mem_e, Binv,
                                                   nullptr, nullptr, Ebf);
  hg_gemm<<<dim3(MPAD / 64, FD / 16), 256, 0, stream>>>(Ebf, Wt1, eWbf, NE);
  hipMemsetAsync(stats, 0, 2 * FD * 4, stream);
  hg_agg_e2n_bf<<<E2N_BLOCKS, 256, 0, stream>>>(eWbf, off_n, mem_n, Dinv, b1, Outbf, stats);
  hg_bn_finalize<<<1, FD, 0, stream>>>(stats, g1, be1, scale1, shift1);

  // ---- layer 2 (BN1+ReLU fused into the gather)
  hg_agg_n2e_bf<1><<<N2E_BLOCKS, 256, 0, stream>>>(Outbf, off_e, mem_e, Binv,
                                                   scale1, shift1, Ebf);
  hg_gemm<<<dim3(MPAD / 64, FD / 16), 256, 0, stream>>>(Ebf, Wt2, eWbf, NE);
  hipMemsetAsync(stats, 0, 2 * FD * 4, stream);
  hg_agg_e2n_bf<<<E2N_BLOCKS, 256, 0, stream>>>(eWbf, off_n, mem_n, Dinv, b2, Outbf, stats);
  hg_bn_finalize<<<1, FD, 0, stream>>>(stats, g2, be2, scale2, shift2);
  hg_apply_bf<<<(NN * FD / 8 + 255) / 256, 256, 0, stream>>>(Outbf, scale2, shift2, out);
}

// Round 3
// 814.756 us; speedup vs baseline: 1.8710x; 1.8710x over previous
//
#include <hip/hip_runtime.h>

#define NN     50000
#define NE     20000
#define NNZV   800000
#define FD     256
#define EPSV   1e-5f
#define MPAD   20032     // NE rounded up to 64 for GEMM tiling

typedef __attribute__((ext_vector_type(8))) __bf16 bf16x8;
typedef __attribute__((ext_vector_type(4))) __bf16 bf16x4;
typedef __attribute__((ext_vector_type(4))) float f32x4;

__device__ __forceinline__ float b2f(unsigned short u) {
  union { unsigned int i; float f; } z; z.i = ((unsigned)u) << 16; return z.f;
}

// ---- CSR construction -------------------------------------------------------

__global__ void hg_hist(const int* __restrict__ nidx, const int* __restrict__ eidx,
                        const float* __restrict__ wedge,
                        int* __restrict__ cnt_e, int* __restrict__ cnt_n,
                        float* __restrict__ Dacc) {
  int i = blockIdx.x * 256 + threadIdx.x;
  if (i >= NNZV) return;
  int e = eidx[i];
  int n = nidx[i];
  atomicAdd(&cnt_e[e], 1);
  atomicAdd(&cnt_n[n], 1);
  atomicAdd(&Dacc[n], wedge[e]);
}

__global__ void hg_exscan(const int* __restrict__ cnt, int n, int* __restrict__ off) {
  __shared__ int lds[1024];
  int t = threadIdx.x;
  int chunk = (n + 1023) >> 10;
  long lo = (long)t * chunk;
  long hi = lo + chunk;
  if (lo > n) lo = n;
  if (hi > n) hi = n;
  int s = 0;
  for (long i = lo; i < hi; ++i) s += cnt[i];
  lds[t] = s;
  for (int d = 1; d < 1024; d <<= 1) {
    __syncthreads();
    int u = (t >= d) ? lds[t - d] : 0;
    int v = lds[t];
    __syncthreads();
    lds[t] = u + v;
  }
  __syncthreads();
  int run = (t == 0) ? 0 : lds[t - 1];
  for (long i = lo; i < hi; ++i) { off[i] = run; run += cnt[i]; }
  if (t == 1023) off[n] = lds[1023];
}

__global__ void hg_scatter(const int* __restrict__ nidx, const int* __restrict__ eidx,
                           const int* __restrict__ off_e, const int* __restrict__ off_n,
                           int* __restrict__ cur_e, int* __restrict__ cur_n,
                           int* __restrict__ mem_e, int* __restrict__ mem_n) {
  int i = blockIdx.x * 256 + threadIdx.x;
  if (i >= NNZV) return;
  int n = nidx[i];
  int e = eidx[i];
  int pe = atomicAdd(&cur_e[e], 1);
  mem_e[off_e[e] + pe] = n;
  int pn = atomicAdd(&cur_n[n], 1);
  mem_n[off_n[n] + pn] = e;
}

__global__ void hg_inv(const int* __restrict__ cnt_e, const float* __restrict__ Dacc,
                       float* __restrict__ Binv, float* __restrict__ Dinv) {
  int i = blockIdx.x * 256 + threadIdx.x;
  if (i < NE) Binv[i] = cnt_e[i] ? 1.0f / (float)cnt_e[i] : 0.0f;
  if (i < NN) {
    float d = Dacc[i];
    Dinv[i] = (d != 0.0f) ? 1.0f / d : 0.0f;
  }
}

// ---- weights to bf16, transposed (Wt[n][k] = W[k][n]) -----------------------

__global__ void hg_wconv(const float* __restrict__ W1, const float* __restrict__ W2,
                         __bf16* __restrict__ Wt1, __bf16* __restrict__ Wt2) {
  int id = blockIdx.x * 256 + threadIdx.x;  // 65536 total
  int n = id >> 8;
  int k = id & 255;
  Wt1[n * FD + k] = (__bf16)W1[k * FD + n];
  Wt2[n * FD + k] = (__bf16)W2[k * FD + n];
}

// ---- x (f32) -> bf16 --------------------------------------------------------

__global__ void hg_x2bf(const float* __restrict__ X, __bf16* __restrict__ Xbf) {
  int idx = blockIdx.x * 256 + threadIdx.x;   // over NN*FD/4
  if (idx >= NN * FD / 4) return;
  float4 v = ((const float4*)X)[idx];
  bf16x4 o = {(__bf16)v.x, (__bf16)v.y, (__bf16)v.z, (__bf16)v.w};
  ((bf16x4*)Xbf)[idx] = o;
}

// ---- node -> edge aggregation: wave per edge, MLP-4 unroll ------------------
// APPLY=1: apply previous layer's BN scale/shift + ReLU to each gathered elem.

template<int APPLY>
__global__ __launch_bounds__(256) void
hg_agg_n2e_bf(const __bf16* __restrict__ Xbf, const int* __restrict__ off_e,
              const int* __restrict__ mem_e, const float* __restrict__ Binv,
              const float* __restrict__ scale, const float* __restrict__ shift,
              __bf16* __restrict__ Ebf) {
  int wid = blockIdx.x * 4 + (threadIdx.x >> 6);   // edge id
  if (wid >= NE) return;
  int lane = threadIdx.x & 63;
  int c = lane * 4;
  float4 sc = {0.f, 0.f, 0.f, 0.f}, sh = {0.f, 0.f, 0.f, 0.f};
  if (APPLY) {
    sc = *(const float4*)(scale + c);
    sh = *(const float4*)(shift + c);
  }
  const unsigned short* Xu = (const unsigned short*)Xbf;
  int lo = off_e[wid], hi = off_e[wid + 1];
  float a0 = 0.f, a1 = 0.f, a2 = 0.f, a3 = 0.f;

#define ACC4(v) do { \
    float f0 = b2f((v).x), f1 = b2f((v).y), f2 = b2f((v).z), f3 = b2f((v).w); \
    if (APPLY) { \
      f0 = fmaxf(fmaf(f0, sc.x, sh.x), 0.f); \
      f1 = fmaxf(fmaf(f1, sc.y, sh.y), 0.f); \
      f2 = fmaxf(fmaf(f2, sc.z, sh.z), 0.f); \
      f3 = fmaxf(fmaf(f3, sc.w, sh.w), 0.f); \
    } \
    a0 += f0; a1 += f1; a2 += f2; a3 += f3; } while (0)

  int m = lo;
  for (; m + 4 <= hi; m += 4) {
    int i0 = mem_e[m], i1 = mem_e[m + 1], i2 = mem_e[m + 2], i3 = mem_e[m + 3];
    ushort4 v0 = *(const ushort4*)(Xu + (size_t)i0 * FD + c);
    ushort4 v1 = *(const ushort4*)(Xu + (size_t)i1 * FD + c);
    ushort4 v2 = *(const ushort4*)(Xu + (size_t)i2 * FD + c);
    ushort4 v3 = *(const ushort4*)(Xu + (size_t)i3 * FD + c);
    ACC4(v0); ACC4(v1); ACC4(v2); ACC4(v3);
  }
  for (; m < hi; ++m) {
    int i0 = mem_e[m];
    ushort4 v0 = *(const ushort4*)(Xu + (size_t)i0 * FD + c);
    ACC4(v0);
  }
  float bi = Binv[wid];
  bf16x4 o = {(__bf16)(a0 * bi), (__bf16)(a1 * bi), (__bf16)(a2 * bi), (__bf16)(a3 * bi)};
  *(bf16x4*)(Ebf + (size_t)wid * FD + c) = o;
}

// ---- GEMM: C[M x 256] = A[M x 256] @ Bt^T, bf16 MFMA, bf16 out --------------

__global__ void hg_gemm(const __bf16* __restrict__ A, const __bf16* __restrict__ Bt,
                        __bf16* __restrict__ C, int Mrows) {
  int tid = threadIdx.x;
  int w = tid >> 6;
  int l = tid & 63;
  int m0 = blockIdx.x * 64 + w * 16;
  int n0 = blockIdx.y * 16;
  int kbase = (l >> 4) * 8;
  const bf16x8* Ap = (const bf16x8*)(A + (size_t)(m0 + (l & 15)) * FD + kbase);
  const bf16x8* Bp = (const bf16x8*)(Bt + (size_t)(n0 + (l & 15)) * FD + kbase);
  f32x4 acc = {0.f, 0.f, 0.f, 0.f};
#pragma unroll
  for (int ks = 0; ks < 8; ++ks) {
    bf16x8 a = Ap[ks * 4];   // +32 bf16 per k-step
    bf16x8 b = Bp[ks * 4];
    acc = __builtin_amdgcn_mfma_f32_16x16x32_bf16(a, b, acc, 0, 0, 0);
  }
  int crow = m0 + (l >> 4) * 4;
  int ccol = n0 + (l & 15);
#pragma unroll
  for (int r = 0; r < 4; ++r) {
    int rr = crow + r;
    if (rr < Mrows) C[(size_t)rr * FD + ccol] = (__bf16)acc[r];
  }
}

// ---- edge -> node aggregation: wave per node, MLP-4 unroll ------------------

__global__ __launch_bounds__(256) void
hg_agg_e2n_bf(const __bf16* __restrict__ eWbf, const int* __restrict__ off_n,
              const int* __restrict__ mem_n, const float* __restrict__ Dinv,
              const float* __restrict__ bias, __bf16* __restrict__ Outbf) {
  int node = blockIdx.x * 4 + (threadIdx.x >> 6);
  if (node >= NN) return;
  int lane = threadIdx.x & 63;
  int c = lane * 4;
  const unsigned short* eWu = (const unsigned short*)eWbf;
  int lo = off_n[node], hi = off_n[node + 1];
  float a0 = 0.f, a1 = 0.f, a2 = 0.f, a3 = 0.f;
  int m = lo;
  for (; m + 4 <= hi; m += 4) {
    int i0 = mem_n[m], i1 = mem_n[m + 1], i2 = mem_n[m + 2], i3 = mem_n[m + 3];
    ushort4 v0 = *(const ushort4*)(eWu + (size_t)i0 * FD + c);
    ushort4 v1 = *(const ushort4*)(eWu + (size_t)i1 * FD + c);
    ushort4 v2 = *(const ushort4*)(eWu + (size_t)i2 * FD + c);
    ushort4 v3 = *(const ushort4*)(eWu + (size_t)i3 * FD + c);
    a0 += b2f(v0.x); a1 += b2f(v0.y); a2 += b2f(v0.z); a3 += b2f(v0.w);
    a0 += b2f(v1.x); a1 += b2f(v1.y); a2 += b2f(v1.z); a3 += b2f(v1.w);
    a0 += b2f(v2.x); a1 += b2f(v2.y); a2 += b2f(v2.z); a3 += b2f(v2.w);
    a0 += b2f(v3.x); a1 += b2f(v3.y); a2 += b2f(v3.z); a3 += b2f(v3.w);
  }
  for (; m < hi; ++m) {
    int i0 = mem_n[m];
    ushort4 v0 = *(const ushort4*)(eWu + (size_t)i0 * FD + c);
    a0 += b2f(v0.x); a1 += b2f(v0.y); a2 += b2f(v0.z); a3 += b2f(v0.w);
  }
  float di = Dinv[node];
  float4 b4 = *(const float4*)(bias + c);
  bf16x4 o = {(__bf16)fmaf(a0, di, b4.x), (__bf16)fmaf(a1, di, b4.y),
              (__bf16)fmaf(a2, di, b4.z), (__bf16)fmaf(a3, di, b4.w)};
  *(bf16x4*)(Outbf + (size_t)node * FD + c) = o;
}

// ---- column stats over Outbf (sum, sumsq) -----------------------------------

__global__ __launch_bounds__(256) void
hg_stats(const __bf16* __restrict__ Outbf, float* __restrict__ stats) {
  int c = threadIdx.x;
  int rpb = (NN + gridDim.x - 1) / gridDim.x;
  int r0 = blockIdx.x * rpb;
  int r1 = r0 + rpb;
  if (r1 > NN) r1 = NN;
  const unsigned short* Ou = (const unsigned short*)Outbf;
  float s = 0.f, q = 0.f;
  for (int r = r0; r < r1; ++r) {
    float v = b2f(Ou[(size_t)r * FD + c]);
    s += v;
    q = fmaf(v, v, q);
  }
  atomicAdd(&stats[c], s);
  atomicAdd(&stats[FD + c], q);
}

// ---- BN finalize + final fused apply/ReLU -----------------------------------

__global__ void hg_bn_finalize(const float* __restrict__ stats, const float* __restrict__ g,
                               const float* __restrict__ be,
                               float* __restrict__ scale, float* __restrict__ shift) {
  int c = threadIdx.x;
  float mu = stats[c] * (1.0f / NN);
  float var = stats[FD + c] * (1.0f / NN) - mu * mu;
  float sc = g[c] * rsqrtf(var + EPSV);
  scale[c] = sc;
  shift[c] = fmaf(-mu, sc, be[c]);
}

__global__ void hg_apply_bf(const __bf16* __restrict__ Outbf, const float* __restrict__ scale,
                            const float* __restrict__ shift, float* __restrict__ H) {
  int idx = blockIdx.x * 256 + threadIdx.x;   // over NN*FD/8
  if (idx >= NN * FD / 8) return;
  ushort4 v0 = ((const ushort4*)Outbf)[idx * 2 + 0];
  ushort4 v1 = ((const ushort4*)Outbf)[idx * 2 + 1];
  int c = (idx & (FD / 8 - 1)) * 8;
  float4 sa = *(const float4*)(scale + c);
  float4 sb = *(const float4*)(scale + c + 4);
  float4 ha = *(const float4*)(shift + c);
  float4 hb = *(const float4*)(shift + c + 4);
  float4 o0, o1;
  o0.x = fmaxf(fmaf(b2f(v0.x), sa.x, ha.x), 0.f);
  o0.y = fmaxf(fmaf(b2f(v0.y), sa.y, ha.y), 0.f);
  o0.z = fmaxf(fmaf(b2f(v0.z), sa.z, ha.z), 0.f);
  o0.w = fmaxf(fmaf(b2f(v0.w), sa.w, ha.w), 0.f);
  o1.x = fmaxf(fmaf(b2f(v1.x), sb.x, hb.x), 0.f);
  o1.y = fmaxf(fmaf(b2f(v1.y), sb.y, hb.y), 0.f);
  o1.z = fmaxf(fmaf(b2f(v1.z), sb.z, hb.z), 0.f);
  o1.w = fmaxf(fmaf(b2f(v1.w), sb.w, hb.w), 0.f);
  ((float4*)H)[idx * 2 + 0] = o0;
  ((float4*)H)[idx * 2 + 1] = o1;
}

// ---- launch -----------------------------------------------------------------

extern "C" void kernel_launch(void* const* d_in, const int* in_sizes, int n_in,
                              void* d_out, int out_size, void* d_ws, size_t ws_size,
                              hipStream_t stream) {
  const float* x    = (const float*)d_in[0];
  const int*   hei  = (const int*)d_in[1];
  const int*   nidx = hei;               // hyperedge_index[0]
  const int*   eidx = hei + NNZV;        // hyperedge_index[1]
  const float* wedge = (const float*)d_in[2];
  const float* W1  = (const float*)d_in[3];
  const float* b1  = (const float*)d_in[4];
  const float* g1  = (const float*)d_in[5];
  const float* be1 = (const float*)d_in[6];
  const float* W2  = (const float*)d_in[7];
  const float* b2  = (const float*)d_in[8];
  const float* g2  = (const float*)d_in[9];
  const float* be2 = (const float*)d_in[10];
  float* out = (float*)d_out;

  char* base = (char*)d_ws;
  size_t cur = 0;
  auto alloc = [&](size_t bytes) -> void* {
    void* p = base + cur;
    cur += (bytes + 255) & ~(size_t)255;
    return p;
  };
  // zero-initialized group (single memset over the span)
  int*   cnt_e = (int*)alloc(NE * 4);
  int*   cnt_n = (int*)alloc(NN * 4);
  int*   cur_e = (int*)alloc(NE * 4);
  int*   cur_n = (int*)alloc(NN * 4);
  float* Dacc  = (float*)alloc(NN * 4);
  size_t zero_span = cur;
  // rest
  int*   off_e = (int*)alloc((NE + 1) * 4);
  int*   off_n = (int*)alloc((NN + 1) * 4);
  int*   mem_e = (int*)alloc((size_t)NNZV * 4);
  int*   mem_n = (int*)alloc((size_t)NNZV * 4);
  float* Dinv  = (float*)alloc(NN * 4);
  float* Binv  = (float*)alloc(NE * 4);
  __bf16* Wt1  = (__bf16*)alloc(FD * FD * 2);
  __bf16* Wt2  = (__bf16*)alloc(FD * FD * 2);
  __bf16* Xbf  = (__bf16*)alloc((size_t)NN * FD * 2);
  __bf16* Ebf  = (__bf16*)alloc((size_t)MPAD * FD * 2);
  __bf16* eWbf = (__bf16*)alloc((size_t)MPAD * FD * 2);
  __bf16* Outbf = (__bf16*)alloc((size_t)NN * FD * 2);
  float* stats = (float*)alloc(2 * FD * 4);
  float* scale1 = (float*)alloc(FD * 4);
  float* shift1 = (float*)alloc(FD * 4);
  float* scale2 = (float*)alloc(FD * 4);
  float* shift2 = (float*)alloc(FD * 4);
  if (cur > ws_size) return;

  hipMemsetAsync(base, 0, zero_span, stream);

  hg_hist<<<(NNZV + 255) / 256, 256, 0, stream>>>(nidx, eidx, wedge, cnt_e, cnt_n, Dacc);
  hg_exscan<<<1, 1024, 0, stream>>>(cnt_e, NE, off_e);
  hg_exscan<<<1, 1024, 0, stream>>>(cnt_n, NN, off_n);
  hg_scatter<<<(NNZV + 255) / 256, 256, 0, stream>>>(nidx, eidx, off_e, off_n,
                                                     cur_e, cur_n, mem_e, mem_n);
  hg_inv<<<(NN + 255) / 256, 256, 0, stream>>>(cnt_e, Dacc, Binv, Dinv);
  hg_wconv<<<FD, 256, 0, stream>>>(W1, W2, Wt1, Wt2);
  hg_x2bf<<<(NN * FD / 4 + 255) / 256, 256, 0, stream>>>(x, Xbf);

  const int N2E_BLOCKS = (NE + 3) / 4;     // wave per edge
  const int E2N_BLOCKS = (NN + 3) / 4;     // wave per node

  // ---- layer 1
  hg_agg_n2e_bf<0><<<N2E_BLOCKS, 256, 0, stream>>>(Xbf, off_e, mem_e, Binv,
                                                   nullptr, nullptr, Ebf);
  hg_gemm<<<dim3(MPAD / 64, FD / 16), 256, 0, stream>>>(Ebf, Wt1, eWbf, NE);
  hg_agg_e2n_bf<<<E2N_BLOCKS, 256, 0, stream>>>(eWbf, off_n, mem_n, Dinv, b1, Outbf);
  hipMemsetAsync(stats, 0, 2 * FD * 4, stream);
  hg_stats<<<256, 256, 0, stream>>>(Outbf, stats);
  hg_bn_finalize<<<1, FD, 0, stream>>>(stats, g1, be1, scale1, shift1);

  // ---- layer 2 (BN1+ReLU fused into the gather)
  hg_agg_n2e_bf<1><<<N2E_BLOCKS, 256, 0, stream>>>(Outbf, off_e, mem_e, Binv,
                                                   scale1, shift1, Ebf);
  hg_gemm<<<dim3(MPAD / 64, FD / 16), 256, 0, stream>>>(Ebf, Wt2, eWbf, NE);
  hg_agg_e2n_bf<<<E2N_BLOCKS, 256, 0, stream>>>(eWbf, off_n, mem_n, Dinv, b2, Outbf);
  hipMemsetAsync(stats, 0, 2 * FD * 4, stream);
  hg_stats<<<256, 256, 0, stream>>>(Outbf, stats);
  hg_bn_finalize<<<1, FD, 0, stream>>>(stats, g2, be2, scale2, shift2);
  hg_apply_bf<<<(NN * FD / 8 + 255) / 256, 256, 0, stream>>>(Outbf, scale2, shift2, out);
}

// Round 4
// 688.635 us; speedup vs baseline: 2.2137x; 1.1831x over previous
//
#include <hip/hip_runtime.h>

#define NN     50000
#define NE     20000
#define NNZV   800000
#define FD     256
#define EPSV   1e-5f
#define MPAD   20032     // NE rounded up to 64 for GEMM tiling
#define NCOPY  32
#define BE     ((NE + 255) / 256)    // 79 scan blocks (edge side)
#define BN     ((NN + 255) / 256)    // 196 scan blocks (node side)

typedef __attribute__((ext_vector_type(8))) __bf16 bf16x8;
typedef __attribute__((ext_vector_type(4))) __bf16 bf16x4;
typedef __attribute__((ext_vector_type(4))) float f32x4;

__device__ __forceinline__ float b2f(unsigned short u) {
  union { unsigned int i; float f; } z; z.i = ((unsigned)u) << 16; return z.f;
}

// ---- CSR construction (privatized, atomic-light) ----------------------------

__global__ void hg_hist(const int* __restrict__ nidx, const int* __restrict__ eidx,
                        const float* __restrict__ wedge,
                        int* __restrict__ cntc_e, int* __restrict__ cntc_n,
                        float* __restrict__ Daccc,
                        int* __restrict__ rank_e, int* __restrict__ rank_n) {
  int i = blockIdx.x * 256 + threadIdx.x;
  if (i >= NNZV) return;
  int copy = blockIdx.x & (NCOPY - 1);
  int e = eidx[i];
  int n = nidx[i];
  rank_e[i] = atomicAdd(&cntc_e[copy * NE + e], 1);
  rank_n[i] = atomicAdd(&cntc_n[copy * NN + n], 1);
  atomicAdd(&Daccc[copy * NN + n], wedge[e]);
}

// sum copies -> totals; in-place within-key prefix over copies; Binv
__global__ void hg_colreduce_e(int* __restrict__ cntc_e, int* __restrict__ total_e,
                               float* __restrict__ Binv) {
  int e = blockIdx.x * 256 + threadIdx.x;
  if (e >= NE) return;
  int run = 0;
#pragma unroll
  for (int c = 0; c < NCOPY; ++c) {
    int v = cntc_e[c * NE + e];
    cntc_e[c * NE + e] = run;
    run += v;
  }
  total_e[e] = run;
  Binv[e] = run ? 1.0f / (float)run : 0.0f;
}

__global__ void hg_colreduce_n(int* __restrict__ cntc_n, const float* __restrict__ Daccc,
                               int* __restrict__ total_n, float* __restrict__ Dinv) {
  int n = blockIdx.x * 256 + threadIdx.x;
  if (n >= NN) return;
  int run = 0;
  float d = 0.f;
#pragma unroll
  for (int c = 0; c < NCOPY; ++c) {
    int v = cntc_n[c * NN + n];
    cntc_n[c * NN + n] = run;
    run += v;
    d += Daccc[c * NN + n];
  }
  total_n[n] = run;
  Dinv[n] = (d != 0.f) ? 1.0f / d : 0.0f;
}

// ---- 3-phase exclusive scan over total_e (BE blocks) and total_n (BN blocks)

__global__ void hg_scan1(const int* __restrict__ total_e, const int* __restrict__ total_n,
                         int* __restrict__ part) {
  __shared__ int lds[256];
  int b = blockIdx.x;
  const int* src;
  int n, idx0;
  if (b < BE) { src = total_e; n = NE; idx0 = b * 256; }
  else        { src = total_n; n = NN; idx0 = (b - BE) * 256; }
  int t = threadIdx.x;
  int idx = idx0 + t;
  lds[t] = (idx < n) ? src[idx] : 0;
  for (int d = 128; d > 0; d >>= 1) {
    __syncthreads();
    if (t < d) lds[t] += lds[t + d];
  }
  if (t == 0) part[b] = lds[0];
}

__global__ void hg_scan2(int* __restrict__ part, int* __restrict__ off_e,
                         int* __restrict__ off_n) {
  __shared__ int lds[256];
  int t = threadIdx.x;
  // edge side (BE parts)
  int v = (t < BE) ? part[t] : 0;
  lds[t] = v;
  for (int d = 1; d < 256; d <<= 1) {
    __syncthreads();
    int u = (t >= d) ? lds[t - d] : 0;
    int w = lds[t];
    __syncthreads();
    lds[t] = u + w;
  }
  __syncthreads();
  if (t < BE) part[t] = lds[t] - v;
  if (t == 255) off_e[NE] = lds[255];
  __syncthreads();
  // node side (BN parts)
  v = (t < BN) ? part[BE + t] : 0;
  lds[t] = v;
  for (int d = 1; d < 256; d <<= 1) {
    __syncthreads();
    int u = (t >= d) ? lds[t - d] : 0;
    int w = lds[t];
    __syncthreads();
    lds[t] = u + w;
  }
  __syncthreads();
  if (t < BN) part[BE + t] = lds[t] - v;
  if (t == 255) off_n[NN] = lds[255];
}

__global__ void hg_scan3(const int* __restrict__ total_e, const int* __restrict__ total_n,
                         const int* __restrict__ part,
                         int* __restrict__ off_e, int* __restrict__ off_n) {
  __shared__ int lds[256];
  int b = blockIdx.x;
  const int* src;
  int* dst;
  int n, idx0;
  if (b < BE) { src = total_e; dst = off_e; n = NE; idx0 = b * 256; }
  else        { src = total_n; dst = off_n; n = NN; idx0 = (b - BE) * 256; }
  int base = part[b];
  int t = threadIdx.x;
  int idx = idx0 + t;
  int v = (idx < n) ? src[idx] : 0;
  lds[t] = v;
  for (int d = 1; d < 256; d <<= 1) {
    __syncthreads();
    int u = (t >= d) ? lds[t - d] : 0;
    int w = lds[t];
    __syncthreads();
    lds[t] = u + w;
  }
  __syncthreads();
  if (idx < n) dst[idx] = base + lds[t] - v;
}

// fold global offsets into the per-copy bases so scatter does 1 read/side
__global__ void hg_addoff(int* __restrict__ cntc_e, int* __restrict__ cntc_n,
                          const int* __restrict__ off_e, const int* __restrict__ off_n) {
  int id = blockIdx.x * 256 + threadIdx.x;
  if (id < NCOPY * NE) {
    cntc_e[id] += off_e[id % NE];
  } else {
    id -= NCOPY * NE;
    if (id < NCOPY * NN) cntc_n[id] += off_n[id % NN];
  }
}

__global__ void hg_scatter(const int* __restrict__ nidx, const int* __restrict__ eidx,
                           const int* __restrict__ cntc_e, const int* __restrict__ cntc_n,
                           const int* __restrict__ rank_e, const int* __restrict__ rank_n,
                           int* __restrict__ mem_e, int* __restrict__ mem_n) {
  int i = blockIdx.x * 256 + threadIdx.x;
  if (i >= NNZV) return;
  int copy = blockIdx.x & (NCOPY - 1);
  int e = eidx[i];
  int n = nidx[i];
  mem_e[cntc_e[copy * NE + e] + rank_e[i]] = n;
  mem_n[cntc_n[copy * NN + n] + rank_n[i]] = e;
}

// ---- weights to bf16, transposed (Wt[n][k] = W[k][n]) -----------------------

__global__ void hg_wconv(const float* __restrict__ W1, const float* __restrict__ W2,
                         __bf16* __restrict__ Wt1, __bf16* __restrict__ Wt2) {
  int id = blockIdx.x * 256 + threadIdx.x;  // 65536 total
  int n = id >> 8;
  int k = id & 255;
  Wt1[n * FD + k] = (__bf16)W1[k * FD + n];
  Wt2[n * FD + k] = (__bf16)W2[k * FD + n];
}

// ---- x (f32) -> bf16 --------------------------------------------------------

__global__ void hg_x2bf(const float* __restrict__ X, __bf16* __restrict__ Xbf) {
  int idx = blockIdx.x * 256 + threadIdx.x;   // over NN*FD/4
  if (idx >= NN * FD / 4) return;
  float4 v = ((const float4*)X)[idx];
  bf16x4 o = {(__bf16)v.x, (__bf16)v.y, (__bf16)v.z, (__bf16)v.w};
  ((bf16x4*)Xbf)[idx] = o;
}

// ---- node -> edge aggregation: wave per edge, MLP-4 unroll ------------------
// APPLY=1: apply previous layer's BN scale/shift + ReLU to each gathered elem.

template<int APPLY>
__global__ __launch_bounds__(256) void
hg_agg_n2e_bf(const __bf16* __restrict__ Xbf, const int* __restrict__ off_e,
              const int* __restrict__ mem_e, const float* __restrict__ Binv,
              const float* __restrict__ scale, const float* __restrict__ shift,
              __bf16* __restrict__ Ebf) {
  int wid = blockIdx.x * 4 + (threadIdx.x >> 6);   // edge id
  if (wid >= NE) return;
  int lane = threadIdx.x & 63;
  int c = lane * 4;
  float4 sc = {0.f, 0.f, 0.f, 0.f}, sh = {0.f, 0.f, 0.f, 0.f};
  if (APPLY) {
    sc = *(const float4*)(scale + c);
    sh = *(const float4*)(shift + c);
  }
  const unsigned short* Xu = (const unsigned short*)Xbf;
  int lo = off_e[wid], hi = off_e[wid + 1];
  float a0 = 0.f, a1 = 0.f, a2 = 0.f, a3 = 0.f;

#define ACC4(v) do { \
    float f0 = b2f((v).x), f1 = b2f((v).y), f2 = b2f((v).z), f3 = b2f((v).w); \
    if (APPLY) { \
      f0 = fmaxf(fmaf(f0, sc.x, sh.x), 0.f); \
      f1 = fmaxf(fmaf(f1, sc.y, sh.y), 0.f); \
      f2 = fmaxf(fmaf(f2, sc.z, sh.z), 0.f); \
      f3 = fmaxf(fmaf(f3, sc.w, sh.w), 0.f); \
    } \
    a0 += f0; a1 += f1; a2 += f2; a3 += f3; } while (0)

  int m = lo;
  for (; m + 4 <= hi; m += 4) {
    int i0 = mem_e[m], i1 = mem_e[m + 1], i2 = mem_e[m + 2], i3 = mem_e[m + 3];
    ushort4 v0 = *(const ushort4*)(Xu + (size_t)i0 * FD + c);
    ushort4 v1 = *(const ushort4*)(Xu + (size_t)i1 * FD + c);
    ushort4 v2 = *(const ushort4*)(Xu + (size_t)i2 * FD + c);
    ushort4 v3 = *(const ushort4*)(Xu + (size_t)i3 * FD + c);
    ACC4(v0); ACC4(v1); ACC4(v2); ACC4(v3);
  }
  for (; m < hi; ++m) {
    int i0 = mem_e[m];
    ushort4 v0 = *(const ushort4*)(Xu + (size_t)i0 * FD + c);
    ACC4(v0);
  }
  float bi = Binv[wid];
  bf16x4 o = {(__bf16)(a0 * bi), (__bf16)(a1 * bi), (__bf16)(a2 * bi), (__bf16)(a3 * bi)};
  *(bf16x4*)(Ebf + (size_t)wid * FD + c) = o;
}

// ---- GEMM: C[M x 256] = A[M x 256] @ Bt^T, bf16 MFMA, bf16 out --------------

__global__ void hg_gemm(const __bf16* __restrict__ A, const __bf16* __restrict__ Bt,
                        __bf16* __restrict__ C, int Mrows) {
  int tid = threadIdx.x;
  int w = tid >> 6;
  int l = tid & 63;
  int m0 = blockIdx.x * 64 + w * 16;
  int n0 = blockIdx.y * 16;
  int kbase = (l >> 4) * 8;
  const bf16x8* Ap = (const bf16x8*)(A + (size_t)(m0 + (l & 15)) * FD + kbase);
  const bf16x8* Bp = (const bf16x8*)(Bt + (size_t)(n0 + (l & 15)) * FD + kbase);
  f32x4 acc = {0.f, 0.f, 0.f, 0.f};
#pragma unroll
  for (int ks = 0; ks < 8; ++ks) {
    bf16x8 a = Ap[ks * 4];   // +32 bf16 per k-step
    bf16x8 b = Bp[ks * 4];
    acc = __builtin_amdgcn_mfma_f32_16x16x32_bf16(a, b, acc, 0, 0, 0);
  }
  int crow = m0 + (l >> 4) * 4;
  int ccol = n0 + (l & 15);
#pragma unroll
  for (int r = 0; r < 4; ++r) {
    int rr = crow + r;
    if (rr < Mrows) C[(size_t)rr * FD + ccol] = (__bf16)acc[r];
  }
}

// ---- edge -> node aggregation: wave per node, MLP-4 unroll ------------------

__global__ __launch_bounds__(256) void
hg_agg_e2n_bf(const __bf16* __restrict__ eWbf, const int* __restrict__ off_n,
              const int* __restrict__ mem_n, const float* __restrict__ Dinv,
              const float* __restrict__ bias, __bf16* __restrict__ Outbf) {
  int node = blockIdx.x * 4 + (threadIdx.x >> 6);
  if (node >= NN) return;
  int lane = threadIdx.x & 63;
  int c = lane * 4;
  const unsigned short* eWu = (const unsigned short*)eWbf;
  int lo = off_n[node], hi = off_n[node + 1];
  float a0 = 0.f, a1 = 0.f, a2 = 0.f, a3 = 0.f;
  int m = lo;
  for (; m + 4 <= hi; m += 4) {
    int i0 = mem_n[m], i1 = mem_n[m + 1], i2 = mem_n[m + 2], i3 = mem_n[m + 3];
    ushort4 v0 = *(const ushort4*)(eWu + (size_t)i0 * FD + c);
    ushort4 v1 = *(const ushort4*)(eWu + (size_t)i1 * FD + c);
    ushort4 v2 = *(const ushort4*)(eWu + (size_t)i2 * FD + c);
    ushort4 v3 = *(const ushort4*)(eWu + (size_t)i3 * FD + c);
    a0 += b2f(v0.x); a1 += b2f(v0.y); a2 += b2f(v0.z); a3 += b2f(v0.w);
    a0 += b2f(v1.x); a1 += b2f(v1.y); a2 += b2f(v1.z); a3 += b2f(v1.w);
    a0 += b2f(v2.x); a1 += b2f(v2.y); a2 += b2f(v2.z); a3 += b2f(v2.w);
    a0 += b2f(v3.x); a1 += b2f(v3.y); a2 += b2f(v3.z); a3 += b2f(v3.w);
  }
  for (; m < hi; ++m) {
    int i0 = mem_n[m];
    ushort4 v0 = *(const ushort4*)(eWu + (size_t)i0 * FD + c);
    a0 += b2f(v0.x); a1 += b2f(v0.y); a2 += b2f(v0.z); a3 += b2f(v0.w);
  }
  float di = Dinv[node];
  float4 b4 = *(const float4*)(bias + c);
  bf16x4 o = {(__bf16)fmaf(a0, di, b4.x), (__bf16)fmaf(a1, di, b4.y),
              (__bf16)fmaf(a2, di, b4.z), (__bf16)fmaf(a3, di, b4.w)};
  *(bf16x4*)(Outbf + (size_t)node * FD + c) = o;
}

// ---- column stats over Outbf (sum, sumsq) -----------------------------------

__global__ __launch_bounds__(256) void
hg_stats(const __bf16* __restrict__ Outbf, float* __restrict__ stats) {
  int c = threadIdx.x;
  int rpb = (NN + gridDim.x - 1) / gridDim.x;
  int r0 = blockIdx.x * rpb;
  int r1 = r0 + rpb;
  if (r1 > NN) r1 = NN;
  const unsigned short* Ou = (const unsigned short*)Outbf;
  float s = 0.f, q = 0.f;
  for (int r = r0; r < r1; ++r) {
    float v = b2f(Ou[(size_t)r * FD + c]);
    s += v;
    q = fmaf(v, v, q);
  }
  atomicAdd(&stats[c], s);
  atomicAdd(&stats[FD + c], q);
}

// ---- BN finalize + final fused apply/ReLU -----------------------------------

__global__ void hg_bn_finalize(const float* __restrict__ stats, const float* __restrict__ g,
                               const float* __restrict__ be,
                               float* __restrict__ scale, float* __restrict__ shift) {
  int c = threadIdx.x;
  float mu = stats[c] * (1.0f / NN);
  float var = stats[FD + c] * (1.0f / NN) - mu * mu;
  float sc = g[c] * rsqrtf(var + EPSV);
  scale[c] = sc;
  shift[c] = fmaf(-mu, sc, be[c]);
}

__global__ void hg_apply_bf(const __bf16* __restrict__ Outbf, const float* __restrict__ scale,
                            const float* __restrict__ shift, float* __restrict__ H) {
  int idx = blockIdx.x * 256 + threadIdx.x;   // over NN*FD/8
  if (idx >= NN * FD / 8) return;
  ushort4 v0 = ((const ushort4*)Outbf)[idx * 2 + 0];
  ushort4 v1 = ((const ushort4*)Outbf)[idx * 2 + 1];
  int c = (idx & (FD / 8 - 1)) * 8;
  float4 sa = *(const float4*)(scale + c);
  float4 sb = *(const float4*)(scale + c + 4);
  float4 ha = *(const float4*)(shift + c);
  float4 hb = *(const float4*)(shift + c + 4);
  float4 o0, o1;
  o0.x = fmaxf(fmaf(b2f(v0.x), sa.x, ha.x), 0.f);
  o0.y = fmaxf(fmaf(b2f(v0.y), sa.y, ha.y), 0.f);
  o0.z = fmaxf(fmaf(b2f(v0.z), sa.z, ha.z), 0.f);
  o0.w = fmaxf(fmaf(b2f(v0.w), sa.w, ha.w), 0.f);
  o1.x = fmaxf(fmaf(b2f(v1.x), sb.x, hb.x), 0.f);
  o1.y = fmaxf(fmaf(b2f(v1.y), sb.y, hb.y), 0.f);
  o1.z = fmaxf(fmaf(b2f(v1.z), sb.z, hb.z), 0.f);
  o1.w = fmaxf(fmaf(b2f(v1.w), sb.w, hb.w), 0.f);
  ((float4*)H)[idx * 2 + 0] = o0;
  ((float4*)H)[idx * 2 + 1] = o1;
}

// ---- launch -----------------------------------------------------------------

extern "C" void kernel_launch(void* const* d_in, const int* in_sizes, int n_in,
                              void* d_out, int out_size, void* d_ws, size_t ws_size,
                              hipStream_t stream) {
  const float* x    = (const float*)d_in[0];
  const int*   hei  = (const int*)d_in[1];
  const int*   nidx = hei;               // hyperedge_index[0]
  const int*   eidx = hei + NNZV;        // hyperedge_index[1]
  const float* wedge = (const float*)d_in[2];
  const float* W1  = (const float*)d_in[3];
  const float* b1  = (const float*)d_in[4];
  const float* g1  = (const float*)d_in[5];
  const float* be1 = (const float*)d_in[6];
  const float* W2  = (const float*)d_in[7];
  const float* b2  = (const float*)d_in[8];
  const float* g2  = (const float*)d_in[9];
  const float* be2 = (const float*)d_in[10];
  float* out = (float*)d_out;

  char* base = (char*)d_ws;
  size_t cur = 0;
  auto alloc = [&](size_t bytes) -> void* {
    void* p = base + cur;
    cur += (bytes + 255) & ~(size_t)255;
    return p;
  };
  // zero-initialized group (single memset over the span)
  int*   cntc_e = (int*)alloc((size_t)NCOPY * NE * 4);
  int*   cntc_n = (int*)alloc((size_t)NCOPY * NN * 4);
  float* Daccc  = (float*)alloc((size_t)NCOPY * NN * 4);
  size_t zero_span = cur;
  // rest
  int*   rank_e = (int*)alloc((size_t)NNZV * 4);
  int*   rank_n = (int*)alloc((size_t)NNZV * 4);
  int*   total_e = (int*)alloc(NE * 4);
  int*   total_n = (int*)alloc(NN * 4);
  int*   part   = (int*)alloc((BE + BN) * 4);
  int*   off_e = (int*)alloc((NE + 1) * 4);
  int*   off_n = (int*)alloc((NN + 1) * 4);
  int*   mem_e = (int*)alloc((size_t)NNZV * 4);
  int*   mem_n = (int*)alloc((size_t)NNZV * 4);
  float* Dinv  = (float*)alloc(NN * 4);
  float* Binv  = (float*)alloc(NE * 4);
  __bf16* Wt1  = (__bf16*)alloc(FD * FD * 2);
  __bf16* Wt2  = (__bf16*)alloc(FD * FD * 2);
  __bf16* Xbf  = (__bf16*)alloc((size_t)NN * FD * 2);
  __bf16* Ebf  = (__bf16*)alloc((size_t)MPAD * FD * 2);
  __bf16* eWbf = (__bf16*)alloc((size_t)MPAD * FD * 2);
  __bf16* Outbf = (__bf16*)alloc((size_t)NN * FD * 2);
  float* stats = (float*)alloc(2 * FD * 4);
  float* scale1 = (float*)alloc(FD * 4);
  float* shift1 = (float*)alloc(FD * 4);
  float* scale2 = (float*)alloc(FD * 4);
  float* shift2 = (float*)alloc(FD * 4);
  if (cur > ws_size) return;

  hipMemsetAsync(base, 0, zero_span, stream);

  hg_hist<<<(NNZV + 255) / 256, 256, 0, stream>>>(nidx, eidx, wedge, cntc_e, cntc_n,
                                                  Daccc, rank_e, rank_n);
  hg_colreduce_e<<<(NE + 255) / 256, 256, 0, stream>>>(cntc_e, total_e, Binv);
  hg_colreduce_n<<<(NN + 255) / 256, 256, 0, stream>>>(cntc_n, Daccc, total_n, Dinv);
  hg_scan1<<<BE + BN, 256, 0, stream>>>(total_e, total_n, part);
  hg_scan2<<<1, 256, 0, stream>>>(part, off_e, off_n);
  hg_scan3<<<BE + BN, 256, 0, stream>>>(total_e, total_n, part, off_e, off_n);
  hg_addoff<<<(NCOPY * (NE + NN) + 255) / 256, 256, 0, stream>>>(cntc_e, cntc_n, off_e, off_n);
  hg_scatter<<<(NNZV + 255) / 256, 256, 0, stream>>>(nidx, eidx, cntc_e, cntc_n,
                                                     rank_e, rank_n, mem_e, mem_n);
  hg_wconv<<<FD, 256, 0, stream>>>(W1, W2, Wt1, Wt2);
  hg_x2bf<<<(NN * FD / 4 + 255) / 256, 256, 0, stream>>>(x, Xbf);

  const int N2E_BLOCKS = (NE + 3) / 4;     // wave per edge
  const int E2N_BLOCKS = (NN + 3) / 4;     // wave per node

  // ---- layer 1
  hg_agg_n2e_bf<0><<<N2E_BLOCKS, 256, 0, stream>>>(Xbf, off_e, mem_e, Binv,
                                                   nullptr, nullptr, Ebf);
  hg_gemm<<<dim3(MPAD / 64, FD / 16), 256, 0, stream>>>(Ebf, Wt1, eWbf, NE);
  hg_agg_e2n_bf<<<E2N_BLOCKS, 256, 0, stream>>>(eWbf, off_n, mem_n, Dinv, b1, Outbf);
  hipMemsetAsync(stats, 0, 2 * FD * 4, stream);
  hg_stats<<<256, 256, 0, stream>>>(Outbf, stats);
  hg_bn_finalize<<<1, FD, 0, stream>>>(stats, g1, be1, scale1, shift1);

  // ---- layer 2 (BN1+ReLU fused into the gather)
  hg_agg_n2e_bf<1><<<N2E_BLOCKS, 256, 0, stream>>>(Outbf, off_e, mem_e, Binv,
                                                   scale1, shift1, Ebf);
  hg_gemm<<<dim3(MPAD / 64, FD / 16), 256, 0, stream>>>(Ebf, Wt2, eWbf, NE);
  hg_agg_e2n_bf<<<E2N_BLOCKS, 256, 0, stream>>>(eWbf, off_n, mem_n, Dinv, b2, Outbf);
  hipMemsetAsync(stats, 0, 2 * FD * 4, stream);
  hg_stats<<<256, 256, 0, stream>>>(Outbf, stats);
  hg_bn_finalize<<<1, FD, 0, stream>>>(stats, g2, be2, scale2, shift2);
  hg_apply_bf<<<(NN * FD / 8 + 255) / 256, 256, 0, stream>>>(Outbf, scale2, shift2, out);
}

// Round 5
// 619.738 us; speedup vs baseline: 2.4598x; 1.1112x over previous
//
#include <hip/hip_runtime.h>

#define NN     50000
#define NE     20000
#define NNZV   800000
#define FD     256
#define EPSV   1e-5f
#define MPAD   20032     // NE rounded up to 64 for GEMM tiling
#define NCPY   128       // histogram copies (= hist blocks)
#define EPB    (NNZV / NCPY)         // 6250 entries per hist block
#define HEC    (NE / 2)              // 10000 packed u32 cells (edge)
#define HNC    (NN / 2)              // 25000 packed u32 cells (node)
#define HTC    (HEC + HNC)           // 35000 cells = 140 KB LDS
#define BE     ((NE + 255) / 256)    // 79 scan blocks (edge side)
#define BN     ((NN + 255) / 256)    // 196 scan blocks (node side)

typedef __attribute__((ext_vector_type(8))) __bf16 bf16x8;
typedef __attribute__((ext_vector_type(4))) __bf16 bf16x4;
typedef __attribute__((ext_vector_type(4))) float f32x4;

__device__ __forceinline__ float b2f(unsigned short u) {
  union { unsigned int i; float f; } z; z.i = ((unsigned)u) << 16; return z.f;
}

// ---- CSR construction: LDS histogram, zero global atomics -------------------
// Block b = copy b owns entries [b*EPB, (b+1)*EPB). Edge and node counters are
// u16 pairs packed in u32 LDS cells; per-(copy,key) counts <= EPB << 65536 and
// per-key totals <= ~100 << 65536, so packed adds never carry across halves.

__global__ __launch_bounds__(256) void
hg_histlds(const int* __restrict__ nidx, const int* __restrict__ eidx,
           unsigned* __restrict__ cntc,
           unsigned short* __restrict__ rank_e16, unsigned short* __restrict__ rank_n16) {
  __shared__ unsigned hist[HTC];   // 140 KB
  int b = blockIdx.x, t = threadIdx.x;
  for (int j = t; j < HTC; j += 256) hist[j] = 0;
  __syncthreads();
  int i0 = b * EPB;
  for (int i = i0 + t; i < i0 + EPB; i += 256) {
    int e = eidx[i];
    int n = nidx[i];
    unsigned se = (e & 1) * 16;
    unsigned sn = (n & 1) * 16;
    unsigned oe = atomicAdd(&hist[e >> 1], 1u << se);
    unsigned on = atomicAdd(&hist[HEC + (n >> 1)], 1u << sn);
    rank_e16[i] = (unsigned short)((oe >> se) & 0xffffu);
    rank_n16[i] = (unsigned short)((on >> sn) & 0xffffu);
  }
  __syncthreads();
  unsigned* dst = cntc + (size_t)b * HTC;
  for (int j = t; j < HTC; j += 256) dst[j] = hist[j];
}

// per-key exclusive prefix over copies (in place, packed) + per-key totals
__global__ void hg_colreduce(unsigned* __restrict__ cntc,
                             int* __restrict__ total_e, int* __restrict__ total_n) {
  int j = blockIdx.x * 256 + threadIdx.x;
  if (j >= HTC) return;
  unsigned run = 0;
#pragma unroll 4
  for (int c = 0; c < NCPY; ++c) {
    unsigned v = cntc[(size_t)c * HTC + j];
    cntc[(size_t)c * HTC + j] = run;
    run += v;                      // packed u16 pair add, no cross-carry
  }
  if (j < HEC) {
    total_e[2 * j]     = run & 0xffffu;
    total_e[2 * j + 1] = run >> 16;
  } else {
    int k = j - HEC;
    total_n[2 * k]     = run & 0xffffu;
    total_n[2 * k + 1] = run >> 16;
  }
}

// ---- 3-phase exclusive scan over total_e (BE blocks) and total_n (BN blocks)

__global__ void hg_scan1(const int* __restrict__ total_e, const int* __restrict__ total_n,
                         int* __restrict__ part) {
  __shared__ int lds[256];
  int b = blockIdx.x;
  const int* src;
  int n, idx0;
  if (b < BE) { src = total_e; n = NE; idx0 = b * 256; }
  else        { src = total_n; n = NN; idx0 = (b - BE) * 256; }
  int t = threadIdx.x;
  int idx = idx0 + t;
  lds[t] = (idx < n) ? src[idx] : 0;
  for (int d = 128; d > 0; d >>= 1) {
    __syncthreads();
    if (t < d) lds[t] += lds[t + d];
  }
  if (t == 0) part[b] = lds[0];
}

__global__ void hg_scan2(int* __restrict__ part, int* __restrict__ off_e,
                         int* __restrict__ off_n) {
  __shared__ int lds[256];
  int t = threadIdx.x;
  int v = (t < BE) ? part[t] : 0;
  lds[t] = v;
  for (int d = 1; d < 256; d <<= 1) {
    __syncthreads();
    int u = (t >= d) ? lds[t - d] : 0;
    int w = lds[t];
    __syncthreads();
    lds[t] = u + w;
  }
  __syncthreads();
  if (t < BE) part[t] = lds[t] - v;
  if (t == 255) off_e[NE] = lds[255];
  __syncthreads();
  v = (t < BN) ? part[BE + t] : 0;
  lds[t] = v;
  for (int d = 1; d < 256; d <<= 1) {
    __syncthreads();
    int u = (t >= d) ? lds[t - d] : 0;
    int w = lds[t];
    __syncthreads();
    lds[t] = u + w;
  }
  __syncthreads();
  if (t < BN) part[BE + t] = lds[t] - v;
  if (t == 255) off_n[NN] = lds[255];
}

__global__ void hg_scan3(const int* __restrict__ total_e, const int* __restrict__ total_n,
                         const int* __restrict__ part,
                         int* __restrict__ off_e, int* __restrict__ off_n) {
  __shared__ int lds[256];
  int b = blockIdx.x;
  const int* src;
  int* dst;
  int n, idx0;
  if (b < BE) { src = total_e; dst = off_e; n = NE; idx0 = b * 256; }
  else        { src = total_n; dst = off_n; n = NN; idx0 = (b - BE) * 256; }
  int base = part[b];
  int t = threadIdx.x;
  int idx = idx0 + t;
  int v = (idx < n) ? src[idx] : 0;
  lds[t] = v;
  for (int d = 1; d < 256; d <<= 1) {
    __syncthreads();
    int u = (t >= d) ? lds[t - d] : 0;
    int w = lds[t];
    __syncthreads();
    lds[t] = u + w;
  }
  __syncthreads();
  if (idx < n) dst[idx] = base + lds[t] - v;
}

// ---- scatter: no atomics (slot = off + copy-prefix + rank) ------------------

__global__ void hg_scatter(const int* __restrict__ nidx, const int* __restrict__ eidx,
                           const unsigned* __restrict__ cntc,
                           const unsigned short* __restrict__ rank_e16,
                           const unsigned short* __restrict__ rank_n16,
                           const int* __restrict__ off_e, const int* __restrict__ off_n,
                           int* __restrict__ mem_e, int* __restrict__ mem_n) {
  int i = blockIdx.x * 256 + threadIdx.x;
  if (i >= NNZV) return;
  unsigned copy = (unsigned)i / EPB;
  int e = eidx[i];
  int n = nidx[i];
  unsigned be = cntc[(size_t)copy * HTC + (e >> 1)];
  be = (be >> ((e & 1) * 16)) & 0xffffu;
  unsigned bn = cntc[(size_t)copy * HTC + HEC + (n >> 1)];
  bn = (bn >> ((n & 1) * 16)) & 0xffffu;
  mem_e[off_e[e] + be + rank_e16[i]] = n;
  mem_n[off_n[n] + bn + rank_n16[i]] = e;
}

// ---- weights to bf16, transposed (Wt[n][k] = W[k][n]) -----------------------

__global__ void hg_wconv(const float* __restrict__ W1, const float* __restrict__ W2,
                         __bf16* __restrict__ Wt1, __bf16* __restrict__ Wt2) {
  int id = blockIdx.x * 256 + threadIdx.x;  // 65536 total
  int n = id >> 8;
  int k = id & 255;
  Wt1[n * FD + k] = (__bf16)W1[k * FD + n];
  Wt2[n * FD + k] = (__bf16)W2[k * FD + n];
}

// ---- x (f32) -> bf16 --------------------------------------------------------

__global__ void hg_x2bf(const float* __restrict__ X, __bf16* __restrict__ Xbf) {
  int idx = blockIdx.x * 256 + threadIdx.x;   // over NN*FD/4
  if (idx >= NN * FD / 4) return;
  float4 v = ((const float4*)X)[idx];
  bf16x4 o = {(__bf16)v.x, (__bf16)v.y, (__bf16)v.z, (__bf16)v.w};
  ((bf16x4*)Xbf)[idx] = o;
}

// ---- node -> edge aggregation: wave per edge, MLP-8 unroll ------------------
// Binv computed inline from CSR extent. APPLY=1: fuse prev layer's BN+ReLU.

template<int APPLY>
__global__ __launch_bounds__(256) void
hg_agg_n2e_bf(const __bf16* __restrict__ Xbf, const int* __restrict__ off_e,
              const int* __restrict__ mem_e,
              const float* __restrict__ scale, const float* __restrict__ shift,
              __bf16* __restrict__ Ebf) {
  int wid = blockIdx.x * 4 + (threadIdx.x >> 6);   // edge id
  if (wid >= NE) return;
  int lane = threadIdx.x & 63;
  int c = lane * 4;
  float4 sc = {0.f, 0.f, 0.f, 0.f}, sh = {0.f, 0.f, 0.f, 0.f};
  if (APPLY) {
    sc = *(const float4*)(scale + c);
    sh = *(const float4*)(shift + c);
  }
  const unsigned short* Xu = (const unsigned short*)Xbf;
  int lo = off_e[wid], hi = off_e[wid + 1];
  float a0 = 0.f, a1 = 0.f, a2 = 0.f, a3 = 0.f;

#define ACC4(v) do { \
    float f0 = b2f((v).x), f1 = b2f((v).y), f2 = b2f((v).z), f3 = b2f((v).w); \
    if (APPLY) { \
      f0 = fmaxf(fmaf(f0, sc.x, sh.x), 0.f); \
      f1 = fmaxf(fmaf(f1, sc.y, sh.y), 0.f); \
      f2 = fmaxf(fmaf(f2, sc.z, sh.z), 0.f); \
      f3 = fmaxf(fmaf(f3, sc.w, sh.w), 0.f); \
    } \
    a0 += f0; a1 += f1; a2 += f2; a3 += f3; } while (0)

  int m = lo;
  for (; m + 8 <= hi; m += 8) {
    int i0 = mem_e[m],     i1 = mem_e[m + 1], i2 = mem_e[m + 2], i3 = mem_e[m + 3];
    int i4 = mem_e[m + 4], i5 = mem_e[m + 5], i6 = mem_e[m + 6], i7 = mem_e[m + 7];
    ushort4 v0 = *(const ushort4*)(Xu + (size_t)i0 * FD + c);
    ushort4 v1 = *(const ushort4*)(Xu + (size_t)i1 * FD + c);
    ushort4 v2 = *(const ushort4*)(Xu + (size_t)i2 * FD + c);
    ushort4 v3 = *(const ushort4*)(Xu + (size_t)i3 * FD + c);
    ushort4 v4 = *(const ushort4*)(Xu + (size_t)i4 * FD + c);
    ushort4 v5 = *(const ushort4*)(Xu + (size_t)i5 * FD + c);
    ushort4 v6 = *(const ushort4*)(Xu + (size_t)i6 * FD + c);
    ushort4 v7 = *(const ushort4*)(Xu + (size_t)i7 * FD + c);
    ACC4(v0); ACC4(v1); ACC4(v2); ACC4(v3);
    ACC4(v4); ACC4(v5); ACC4(v6); ACC4(v7);
  }
  for (; m + 4 <= hi; m += 4) {
    int i0 = mem_e[m], i1 = mem_e[m + 1], i2 = mem_e[m + 2], i3 = mem_e[m + 3];
    ushort4 v0 = *(const ushort4*)(Xu + (size_t)i0 * FD + c);
    ushort4 v1 = *(const ushort4*)(Xu + (size_t)i1 * FD + c);
    ushort4 v2 = *(const ushort4*)(Xu + (size_t)i2 * FD + c);
    ushort4 v3 = *(const ushort4*)(Xu + (size_t)i3 * FD + c);
    ACC4(v0); ACC4(v1); ACC4(v2); ACC4(v3);
  }
  for (; m < hi; ++m) {
    int i0 = mem_e[m];
    ushort4 v0 = *(const ushort4*)(Xu + (size_t)i0 * FD + c);
    ACC4(v0);
  }
  int cnt = hi - lo;
  float bi = cnt ? 1.0f / (float)cnt : 0.0f;
  bf16x4 o = {(__bf16)(a0 * bi), (__bf16)(a1 * bi), (__bf16)(a2 * bi), (__bf16)(a3 * bi)};
  *(bf16x4*)(Ebf + (size_t)wid * FD + c) = o;
}

// ---- GEMM: C[M x 256] = A[M x 256] @ Bt^T, bf16 MFMA, bf16 out --------------

__global__ void hg_gemm(const __bf16* __restrict__ A, const __bf16* __restrict__ Bt,
                        __bf16* __restrict__ C, int Mrows) {
  int tid = threadIdx.x;
  int w = tid >> 6;
  int l = tid & 63;
  int m0 = blockIdx.x * 64 + w * 16;
  int n0 = blockIdx.y * 16;
  int kbase = (l >> 4) * 8;
  const bf16x8* Ap = (const bf16x8*)(A + (size_t)(m0 + (l & 15)) * FD + kbase);
  const bf16x8* Bp = (const bf16x8*)(Bt + (size_t)(n0 + (l & 15)) * FD + kbase);
  f32x4 acc = {0.f, 0.f, 0.f, 0.f};
#pragma unroll
  for (int ks = 0; ks < 8; ++ks) {
    bf16x8 a = Ap[ks * 4];   // +32 bf16 per k-step
    bf16x8 b = Bp[ks * 4];
    acc = __builtin_amdgcn_mfma_f32_16x16x32_bf16(a, b, acc, 0, 0, 0);
  }
  int crow = m0 + (l >> 4) * 4;
  int ccol = n0 + (l & 15);
#pragma unroll
  for (int r = 0; r < 4; ++r) {
    int rr = crow + r;
    if (rr < Mrows) C[(size_t)rr * FD + ccol] = (__bf16)acc[r];
  }
}

// ---- edge -> node aggregation: wave per node, MLP-8, inline D ---------------

__global__ __launch_bounds__(256) void
hg_agg_e2n_bf(const __bf16* __restrict__ eWbf, const int* __restrict__ off_n,
              const int* __restrict__ mem_n, const float* __restrict__ wedge,
              const float* __restrict__ bias, __bf16* __restrict__ Outbf) {
  int node = blockIdx.x * 4 + (threadIdx.x >> 6);
  if (node >= NN) return;
  int lane = threadIdx.x & 63;
  int c = lane * 4;
  const unsigned short* eWu = (const unsigned short*)eWbf;
  int lo = off_n[node], hi = off_n[node + 1];
  float a0 = 0.f, a1 = 0.f, a2 = 0.f, a3 = 0.f;
  float dw = 0.f;
  int m = lo;
  for (; m + 8 <= hi; m += 8) {
    int i0 = mem_n[m],     i1 = mem_n[m + 1], i2 = mem_n[m + 2], i3 = mem_n[m + 3];
    int i4 = mem_n[m + 4], i5 = mem_n[m + 5], i6 = mem_n[m + 6], i7 = mem_n[m + 7];
    ushort4 v0 = *(const ushort4*)(eWu + (size_t)i0 * FD + c);
    ushort4 v1 = *(const ushort4*)(eWu + (size_t)i1 * FD + c);
    ushort4 v2 = *(const ushort4*)(eWu + (size_t)i2 * FD + c);
    ushort4 v3 = *(const ushort4*)(eWu + (size_t)i3 * FD + c);
    ushort4 v4 = *(const ushort4*)(eWu + (size_t)i4 * FD + c);
    ushort4 v5 = *(const ushort4*)(eWu + (size_t)i5 * FD + c);
    ushort4 v6 = *(const ushort4*)(eWu + (size_t)i6 * FD + c);
    ushort4 v7 = *(const ushort4*)(eWu + (size_t)i7 * FD + c);
    dw += wedge[i0] + wedge[i1] + wedge[i2] + wedge[i3]
        + wedge[i4] + wedge[i5] + wedge[i6] + wedge[i7];
    a0 += b2f(v0.x); a1 += b2f(v0.y); a2 += b2f(v0.z); a3 += b2f(v0.w);
    a0 += b2f(v1.x); a1 += b2f(v1.y); a2 += b2f(v1.z); a3 += b2f(v1.w);
    a0 += b2f(v2.x); a1 += b2f(v2.y); a2 += b2f(v2.z); a3 += b2f(v2.w);
    a0 += b2f(v3.x); a1 += b2f(v3.y); a2 += b2f(v3.z); a3 += b2f(v3.w);
    a0 += b2f(v4.x); a1 += b2f(v4.y); a2 += b2f(v4.z); a3 += b2f(v4.w);
    a0 += b2f(v5.x); a1 += b2f(v5.y); a2 += b2f(v5.z); a3 += b2f(v5.w);
    a0 += b2f(v6.x); a1 += b2f(v6.y); a2 += b2f(v6.z); a3 += b2f(v6.w);
    a0 += b2f(v7.x); a1 += b2f(v7.y); a2 += b2f(v7.z); a3 += b2f(v7.w);
  }
  for (; m < hi; ++m) {
    int i0 = mem_n[m];
    ushort4 v0 = *(const ushort4*)(eWu + (size_t)i0 * FD + c);
    dw += wedge[i0];
    a0 += b2f(v0.x); a1 += b2f(v0.y); a2 += b2f(v0.z); a3 += b2f(v0.w);
  }
  float di = (dw != 0.f) ? 1.0f / dw : 0.0f;
  float4 b4 = *(const float4*)(bias + c);
  bf16x4 o = {(__bf16)fmaf(a0, di, b4.x), (__bf16)fmaf(a1, di, b4.y),
              (__bf16)fmaf(a2, di, b4.z), (__bf16)fmaf(a3, di, b4.w)};
  *(bf16x4*)(Outbf + (size_t)node * FD + c) = o;
}

// ---- column stats over Outbf (sum, sumsq) -----------------------------------

__global__ __launch_bounds__(256) void
hg_stats(const __bf16* __restrict__ Outbf, float* __restrict__ stats) {
  int c = threadIdx.x;
  int rpb = (NN + gridDim.x - 1) / gridDim.x;
  int r0 = blockIdx.x * rpb;
  int r1 = r0 + rpb;
  if (r1 > NN) r1 = NN;
  const unsigned short* Ou = (const unsigned short*)Outbf;
  float s = 0.f, q = 0.f;
  for (int r = r0; r < r1; ++r) {
    float v = b2f(Ou[(size_t)r * FD + c]);
    s += v;
    q = fmaf(v, v, q);
  }
  atomicAdd(&stats[c], s);
  atomicAdd(&stats[FD + c], q);
}

// ---- BN finalize + final fused apply/ReLU -----------------------------------

__global__ void hg_bn_finalize(const float* __restrict__ stats, const float* __restrict__ g,
                               const float* __restrict__ be,
                               float* __restrict__ scale, float* __restrict__ shift) {
  int c = threadIdx.x;
  float mu = stats[c] * (1.0f / NN);
  float var = stats[FD + c] * (1.0f / NN) - mu * mu;
  float sc = g[c] * rsqrtf(var + EPSV);
  scale[c] = sc;
  shift[c] = fmaf(-mu, sc, be[c]);
}

__global__ void hg_apply_bf(const __bf16* __restrict__ Outbf, const float* __restrict__ scale,
                            const float* __restrict__ shift, float* __restrict__ H) {
  int idx = blockIdx.x * 256 + threadIdx.x;   // over NN*FD/8
  if (idx >= NN * FD / 8) return;
  ushort4 v0 = ((const ushort4*)Outbf)[idx * 2 + 0];
  ushort4 v1 = ((const ushort4*)Outbf)[idx * 2 + 1];
  int c = (idx & (FD / 8 - 1)) * 8;
  float4 sa = *(const float4*)(scale + c);
  float4 sb = *(const float4*)(scale + c + 4);
  float4 ha = *(const float4*)(shift + c);
  float4 hb = *(const float4*)(shift + c + 4);
  float4 o0, o1;
  o0.x = fmaxf(fmaf(b2f(v0.x), sa.x, ha.x), 0.f);
  o0.y = fmaxf(fmaf(b2f(v0.y), sa.y, ha.y), 0.f);
  o0.z = fmaxf(fmaf(b2f(v0.z), sa.z, ha.z), 0.f);
  o0.w = fmaxf(fmaf(b2f(v0.w), sa.w, ha.w), 0.f);
  o1.x = fmaxf(fmaf(b2f(v1.x), sb.x, hb.x), 0.f);
  o1.y = fmaxf(fmaf(b2f(v1.y), sb.y, hb.y), 0.f);
  o1.z = fmaxf(fmaf(b2f(v1.z), sb.z, hb.z), 0.f);
  o1.w = fmaxf(fmaf(b2f(v1.w), sb.w, hb.w), 0.f);
  ((float4*)H)[idx * 2 + 0] = o0;
  ((float4*)H)[idx * 2 + 1] = o1;
}

// ---- launch -----------------------------------------------------------------

extern "C" void kernel_launch(void* const* d_in, const int* in_sizes, int n_in,
                              void* d_out, int out_size, void* d_ws, size_t ws_size,
                              hipStream_t stream) {
  const float* x    = (const float*)d_in[0];
  const int*   hei  = (const int*)d_in[1];
  const int*   nidx = hei;               // hyperedge_index[0]
  const int*   eidx = hei + NNZV;        // hyperedge_index[1]
  const float* wedge = (const float*)d_in[2];
  const float* W1  = (const float*)d_in[3];
  const float* b1  = (const float*)d_in[4];
  const float* g1  = (const float*)d_in[5];
  const float* be1 = (const float*)d_in[6];
  const float* W2  = (const float*)d_in[7];
  const float* b2  = (const float*)d_in[8];
  const float* g2  = (const float*)d_in[9];
  const float* be2 = (const float*)d_in[10];
  float* out = (float*)d_out;

  char* base = (char*)d_ws;
  size_t cur = 0;
  auto alloc = [&](size_t bytes) -> void* {
    void* p = base + cur;
    cur += (bytes + 255) & ~(size_t)255;
    return p;
  };
  unsigned* cntc = (unsigned*)alloc((size_t)NCPY * HTC * 4);   // 17.9 MB
  unsigned short* rank_e16 = (unsigned short*)alloc((size_t)NNZV * 2);
  unsigned short* rank_n16 = (unsigned short*)alloc((size_t)NNZV * 2);
  int*   total_e = (int*)alloc(NE * 4);
  int*   total_n = (int*)alloc(NN * 4);
  int*   part  = (int*)alloc((BE + BN) * 4);
  int*   off_e = (int*)alloc((NE + 1) * 4);
  int*   off_n = (int*)alloc((NN + 1) * 4);
  int*   mem_e = (int*)alloc((size_t)NNZV * 4);
  int*   mem_n = (int*)alloc((size_t)NNZV * 4);
  __bf16* Wt1  = (__bf16*)alloc(FD * FD * 2);
  __bf16* Wt2  = (__bf16*)alloc(FD * FD * 2);
  __bf16* Xbf  = (__bf16*)alloc((size_t)NN * FD * 2);
  __bf16* Ebf  = (__bf16*)alloc((size_t)MPAD * FD * 2);
  __bf16* eWbf = (__bf16*)alloc((size_t)MPAD * FD * 2);
  __bf16* Outbf = (__bf16*)alloc((size_t)NN * FD * 2);
  float* stats = (float*)alloc(2 * FD * 4);
  float* scale1 = (float*)alloc(FD * 4);
  float* shift1 = (float*)alloc(FD * 4);
  float* scale2 = (float*)alloc(FD * 4);
  float* shift2 = (float*)alloc(FD * 4);
  if (cur > ws_size) return;

  // CSR build (no global atomics anywhere)
  hg_histlds<<<NCPY, 256, 0, stream>>>(nidx, eidx, cntc, rank_e16, rank_n16);
  hg_colreduce<<<(HTC + 255) / 256, 256, 0, stream>>>(cntc, total_e, total_n);
  hg_scan1<<<BE + BN, 256, 0, stream>>>(total_e, total_n, part);
  hg_scan2<<<1, 256, 0, stream>>>(part, off_e, off_n);
  hg_scan3<<<BE + BN, 256, 0, stream>>>(total_e, total_n, part, off_e, off_n);
  hg_scatter<<<(NNZV + 255) / 256, 256, 0, stream>>>(nidx, eidx, cntc, rank_e16, rank_n16,
                                                     off_e, off_n, mem_e, mem_n);
  hg_wconv<<<FD, 256, 0, stream>>>(W1, W2, Wt1, Wt2);
  hg_x2bf<<<(NN * FD / 4 + 255) / 256, 256, 0, stream>>>(x, Xbf);

  const int N2E_BLOCKS = (NE + 3) / 4;     // wave per edge
  const int E2N_BLOCKS = (NN + 3) / 4;     // wave per node

  // ---- layer 1
  hg_agg_n2e_bf<0><<<N2E_BLOCKS, 256, 0, stream>>>(Xbf, off_e, mem_e, nullptr, nullptr, Ebf);
  hg_gemm<<<dim3(MPAD / 64, FD / 16), 256, 0, stream>>>(Ebf, Wt1, eWbf, NE);
  hg_agg_e2n_bf<<<E2N_BLOCKS, 256, 0, stream>>>(eWbf, off_n, mem_n, wedge, b1, Outbf);
  hipMemsetAsync(stats, 0, 2 * FD * 4, stream);
  hg_stats<<<256, 256, 0, stream>>>(Outbf, stats);
  hg_bn_finalize<<<1, FD, 0, stream>>>(stats, g1, be1, scale1, shift1);

  // ---- layer 2 (BN1+ReLU fused into the gather)
  hg_agg_n2e_bf<1><<<N2E_BLOCKS, 256, 0, stream>>>(Outbf, off_e, mem_e, scale1, shift1, Ebf);
  hg_gemm<<<dim3(MPAD / 64, FD / 16), 256, 0, stream>>>(Ebf, Wt2, eWbf, NE);
  hg_agg_e2n_bf<<<E2N_BLOCKS, 256, 0, stream>>>(eWbf, off_n, mem_n, wedge, b2, Outbf);
  hipMemsetAsync(stats, 0, 2 * FD * 4, stream);
  hg_stats<<<256, 256, 0, stream>>>(Outbf, stats);
  hg_bn_finalize<<<1, FD, 0, stream>>>(stats, g2, be2, scale2, shift2);
  hg_apply_bf<<<(NN * FD / 8 + 255) / 256, 256, 0, stream>>>(Outbf, scale2, shift2, out);
}

// Round 6
// 589.448 us; speedup vs baseline: 2.5862x; 1.0514x over previous
//
#include <hip/hip_runtime.h>

#define NN     50000
#define NE     20000
#define NNZV   800000
#define FD     256
#define EPSV   1e-5f
#define MPAD   20032     // NE rounded up to 64 for GEMM tiling
#define NCPY   128       // histogram copies (= hist blocks)
#define EPB    (NNZV / NCPY)         // 6250 entries per hist block
#define HEC    (NE / 2)              // 10000 packed u32 cells (edge)
#define HNC    (NN / 2)              // 25000 packed u32 cells (node)
#define HTC    (HEC + HNC)           // 35000 cells = 140 KB LDS
#define BE     ((NE + 255) / 256)    // 79 scan blocks (edge side)
#define BN     ((NN + 255) / 256)    // 196 scan blocks (node side)

typedef __attribute__((ext_vector_type(8))) __bf16 bf16x8;
typedef __attribute__((ext_vector_type(4))) __bf16 bf16x4;
typedef __attribute__((ext_vector_type(4))) float f32x4;

__device__ __forceinline__ float b2f(unsigned short u) {
  union { unsigned int i; float f; } z; z.i = ((unsigned)u) << 16; return z.f;
}

// ---- CSR construction: LDS histogram, zero global atomics -------------------

__global__ __launch_bounds__(256) void
hg_histlds(const int* __restrict__ nidx, const int* __restrict__ eidx,
           unsigned* __restrict__ cntc,
           unsigned short* __restrict__ rank_e16, unsigned short* __restrict__ rank_n16) {
  __shared__ unsigned hist[HTC];   // 140 KB
  int b = blockIdx.x, t = threadIdx.x;
  for (int j = t; j < HTC; j += 256) hist[j] = 0;
  __syncthreads();
  int i0 = b * EPB;
  for (int i = i0 + t; i < i0 + EPB; i += 256) {
    int e = eidx[i];
    int n = nidx[i];
    unsigned se = (e & 1) * 16;
    unsigned sn = (n & 1) * 16;
    unsigned oe = atomicAdd(&hist[e >> 1], 1u << se);
    unsigned on = atomicAdd(&hist[HEC + (n >> 1)], 1u << sn);
    rank_e16[i] = (unsigned short)((oe >> se) & 0xffffu);
    rank_n16[i] = (unsigned short)((on >> sn) & 0xffffu);
  }
  __syncthreads();
  unsigned* dst = cntc + (size_t)b * HTC;
  for (int j = t; j < HTC; j += 256) dst[j] = hist[j];
}

// per-key exclusive prefix over copies (in place, packed) + per-key totals
__global__ void hg_colreduce(unsigned* __restrict__ cntc,
                             int* __restrict__ total_e, int* __restrict__ total_n) {
  int j = blockIdx.x * 256 + threadIdx.x;
  if (j >= HTC) return;
  unsigned run = 0;
#pragma unroll 4
  for (int c = 0; c < NCPY; ++c) {
    unsigned v = cntc[(size_t)c * HTC + j];
    cntc[(size_t)c * HTC + j] = run;
    run += v;                      // packed u16 pair add, no cross-carry
  }
  if (j < HEC) {
    total_e[2 * j]     = run & 0xffffu;
    total_e[2 * j + 1] = run >> 16;
  } else {
    int k = j - HEC;
    total_n[2 * k]     = run & 0xffffu;
    total_n[2 * k + 1] = run >> 16;
  }
}

// ---- 3-phase exclusive scan over total_e (BE blocks) and total_n (BN blocks)

__global__ void hg_scan1(const int* __restrict__ total_e, const int* __restrict__ total_n,
                         int* __restrict__ part) {
  __shared__ int lds[256];
  int b = blockIdx.x;
  const int* src;
  int n, idx0;
  if (b < BE) { src = total_e; n = NE; idx0 = b * 256; }
  else        { src = total_n; n = NN; idx0 = (b - BE) * 256; }
  int t = threadIdx.x;
  int idx = idx0 + t;
  lds[t] = (idx < n) ? src[idx] : 0;
  for (int d = 128; d > 0; d >>= 1) {
    __syncthreads();
    if (t < d) lds[t] += lds[t + d];
  }
  if (t == 0) part[b] = lds[0];
}

__global__ void hg_scan2(int* __restrict__ part, int* __restrict__ off_e,
                         int* __restrict__ off_n) {
  __shared__ int lds[256];
  int t = threadIdx.x;
  int v = (t < BE) ? part[t] : 0;
  lds[t] = v;
  for (int d = 1; d < 256; d <<= 1) {
    __syncthreads();
    int u = (t >= d) ? lds[t - d] : 0;
    int w = lds[t];
    __syncthreads();
    lds[t] = u + w;
  }
  __syncthreads();
  if (t < BE) part[t] = lds[t] - v;
  if (t == 255) off_e[NE] = lds[255];
  __syncthreads();
  v = (t < BN) ? part[BE + t] : 0;
  lds[t] = v;
  for (int d = 1; d < 256; d <<= 1) {
    __syncthreads();
    int u = (t >= d) ? lds[t - d] : 0;
    int w = lds[t];
    __syncthreads();
    lds[t] = u + w;
  }
  __syncthreads();
  if (t < BN) part[BE + t] = lds[t] - v;
  if (t == 255) off_n[NN] = lds[255];
}

__global__ void hg_scan3(const int* __restrict__ total_e, const int* __restrict__ total_n,
                         const int* __restrict__ part,
                         int* __restrict__ off_e, int* __restrict__ off_n) {
  __shared__ int lds[256];
  int b = blockIdx.x;
  const int* src;
  int* dst;
  int n, idx0;
  if (b < BE) { src = total_e; dst = off_e; n = NE; idx0 = b * 256; }
  else        { src = total_n; dst = off_n; n = NN; idx0 = (b - BE) * 256; }
  int base = part[b];
  int t = threadIdx.x;
  int idx = idx0 + t;
  int v = (idx < n) ? src[idx] : 0;
  lds[t] = v;
  for (int d = 1; d < 256; d <<= 1) {
    __syncthreads();
    int u = (t >= d) ? lds[t - d] : 0;
    int w = lds[t];
    __syncthreads();
    lds[t] = u + w;
  }
  __syncthreads();
  if (idx < n) dst[idx] = base + lds[t] - v;
}

// ---- scatter: no atomics (slot = off + copy-prefix + rank) ------------------

__global__ void hg_scatter(const int* __restrict__ nidx, const int* __restrict__ eidx,
                           const unsigned* __restrict__ cntc,
                           const unsigned short* __restrict__ rank_e16,
                           const unsigned short* __restrict__ rank_n16,
                           const int* __restrict__ off_e, const int* __restrict__ off_n,
                           int* __restrict__ mem_e, int* __restrict__ mem_n) {
  int i = blockIdx.x * 256 + threadIdx.x;
  if (i >= NNZV) return;
  unsigned copy = (unsigned)i / EPB;
  int e = eidx[i];
  int n = nidx[i];
  unsigned be = cntc[(size_t)copy * HTC + (e >> 1)];
  be = (be >> ((e & 1) * 16)) & 0xffffu;
  unsigned bn = cntc[(size_t)copy * HTC + HEC + (n >> 1)];
  bn = (bn >> ((n & 1) * 16)) & 0xffffu;
  mem_e[off_e[e] + be + rank_e16[i]] = n;
  mem_n[off_n[n] + bn + rank_n16[i]] = e;
}

// ---- fused prep: Wt (transposed bf16 weights) + x -> bf16 -------------------

__global__ void hg_prep(const float* __restrict__ W1, const float* __restrict__ W2,
                        __bf16* __restrict__ Wt1, __bf16* __restrict__ Wt2,
                        const float* __restrict__ X, __bf16* __restrict__ Xbf) {
  int bid = blockIdx.x;
  if (bid < FD) {
    int id = bid * 256 + threadIdx.x;
    int n = id >> 8;
    int k = id & 255;
    Wt1[n * FD + k] = (__bf16)W1[k * FD + n];
    Wt2[n * FD + k] = (__bf16)W2[k * FD + n];
  } else {
    int idx = (bid - FD) * 256 + threadIdx.x;
    if (idx < NN * FD / 4) {
      float4 v = ((const float4*)X)[idx];
      bf16x4 o = {(__bf16)v.x, (__bf16)v.y, (__bf16)v.z, (__bf16)v.w};
      ((bf16x4*)Xbf)[idx] = o;
    }
  }
}

// ---- node -> edge aggregation: wave per edge, MLP-8 unroll ------------------

template<int APPLY>
__global__ __launch_bounds__(256) void
hg_agg_n2e_bf(const __bf16* __restrict__ Xbf, const int* __restrict__ off_e,
              const int* __restrict__ mem_e,
              const float* __restrict__ scale, const float* __restrict__ shift,
              __bf16* __restrict__ Ebf) {
  int wid = blockIdx.x * 4 + (threadIdx.x >> 6);   // edge id
  if (wid >= NE) return;
  int lane = threadIdx.x & 63;
  int c = lane * 4;
  float4 sc = {0.f, 0.f, 0.f, 0.f}, sh = {0.f, 0.f, 0.f, 0.f};
  if (APPLY) {
    sc = *(const float4*)(scale + c);
    sh = *(const float4*)(shift + c);
  }
  const unsigned short* Xu = (const unsigned short*)Xbf;
  int lo = off_e[wid], hi = off_e[wid + 1];
  float a0 = 0.f, a1 = 0.f, a2 = 0.f, a3 = 0.f;

#define ACC4(v) do { \
    float f0 = b2f((v).x), f1 = b2f((v).y), f2 = b2f((v).z), f3 = b2f((v).w); \
    if (APPLY) { \
      f0 = fmaxf(fmaf(f0, sc.x, sh.x), 0.f); \
      f1 = fmaxf(fmaf(f1, sc.y, sh.y), 0.f); \
      f2 = fmaxf(fmaf(f2, sc.z, sh.z), 0.f); \
      f3 = fmaxf(fmaf(f3, sc.w, sh.w), 0.f); \
    } \
    a0 += f0; a1 += f1; a2 += f2; a3 += f3; } while (0)

  int m = lo;
  for (; m + 8 <= hi; m += 8) {
    int i0 = mem_e[m],     i1 = mem_e[m + 1], i2 = mem_e[m + 2], i3 = mem_e[m + 3];
    int i4 = mem_e[m + 4], i5 = mem_e[m + 5], i6 = mem_e[m + 6], i7 = mem_e[m + 7];
    ushort4 v0 = *(const ushort4*)(Xu + (size_t)i0 * FD + c);
    ushort4 v1 = *(const ushort4*)(Xu + (size_t)i1 * FD + c);
    ushort4 v2 = *(const ushort4*)(Xu + (size_t)i2 * FD + c);
    ushort4 v3 = *(const ushort4*)(Xu + (size_t)i3 * FD + c);
    ushort4 v4 = *(const ushort4*)(Xu + (size_t)i4 * FD + c);
    ushort4 v5 = *(const ushort4*)(Xu + (size_t)i5 * FD + c);
    ushort4 v6 = *(const ushort4*)(Xu + (size_t)i6 * FD + c);
    ushort4 v7 = *(const ushort4*)(Xu + (size_t)i7 * FD + c);
    ACC4(v0); ACC4(v1); ACC4(v2); ACC4(v3);
    ACC4(v4); ACC4(v5); ACC4(v6); ACC4(v7);
  }
  for (; m + 4 <= hi; m += 4) {
    int i0 = mem_e[m], i1 = mem_e[m + 1], i2 = mem_e[m + 2], i3 = mem_e[m + 3];
    ushort4 v0 = *(const ushort4*)(Xu + (size_t)i0 * FD + c);
    ushort4 v1 = *(const ushort4*)(Xu + (size_t)i1 * FD + c);
    ushort4 v2 = *(const ushort4*)(Xu + (size_t)i2 * FD + c);
    ushort4 v3 = *(const ushort4*)(Xu + (size_t)i3 * FD + c);
    ACC4(v0); ACC4(v1); ACC4(v2); ACC4(v3);
  }
  for (; m < hi; ++m) {
    int i0 = mem_e[m];
    ushort4 v0 = *(const ushort4*)(Xu + (size_t)i0 * FD + c);
    ACC4(v0);
  }
  int cnt = hi - lo;
  float bi = cnt ? 1.0f / (float)cnt : 0.0f;
  bf16x4 o = {(__bf16)(a0 * bi), (__bf16)(a1 * bi), (__bf16)(a2 * bi), (__bf16)(a3 * bi)};
  *(bf16x4*)(Ebf + (size_t)wid * FD + c) = o;
}

// ---- GEMM: C[M x 256] = A[M x 256] @ Bt^T, A-reuse across all N -------------
// grid (MPAD/64, 4); block = 4 waves; wave computes 16 rows x 64 cols.
// A-fragment loaded ONCE per k-step, reused for 4 B-fragments (A traffic 1x).
// B (128 KB) is L2-hot and streamed per wave.

__global__ __launch_bounds__(256) void
hg_gemm(const __bf16* __restrict__ A, const __bf16* __restrict__ Bt,
        __bf16* __restrict__ C, int Mrows) {
  int w = threadIdx.x >> 6, l = threadIdx.x & 63;
  int m0 = blockIdx.x * 64 + w * 16;
  int n0 = blockIdx.y * 64;
  int kb = (l >> 4) * 8;
  const bf16x8* Ap = (const bf16x8*)(A + (size_t)(m0 + (l & 15)) * FD + kb);
  const __bf16* Bbase = Bt + (size_t)(n0 + (l & 15)) * FD + kb;
  f32x4 acc0 = {0.f, 0.f, 0.f, 0.f}, acc1 = {0.f, 0.f, 0.f, 0.f};
  f32x4 acc2 = {0.f, 0.f, 0.f, 0.f}, acc3 = {0.f, 0.f, 0.f, 0.f};
#pragma unroll
  for (int ks = 0; ks < 8; ++ks) {
    bf16x8 a = Ap[ks * 4];                       // +32 bf16 per k-step
    bf16x8 b0 = *(const bf16x8*)(Bbase + (size_t)( 0) * FD + ks * 32);
    bf16x8 b1 = *(const bf16x8*)(Bbase + (size_t)(16) * FD + ks * 32);
    bf16x8 b2 = *(const bf16x8*)(Bbase + (size_t)(32) * FD + ks * 32);
    bf16x8 b3 = *(const bf16x8*)(Bbase + (size_t)(48) * FD + ks * 32);
    acc0 = __builtin_amdgcn_mfma_f32_16x16x32_bf16(a, b0, acc0, 0, 0, 0);
    acc1 = __builtin_amdgcn_mfma_f32_16x16x32_bf16(a, b1, acc1, 0, 0, 0);
    acc2 = __builtin_amdgcn_mfma_f32_16x16x32_bf16(a, b2, acc2, 0, 0, 0);
    acc3 = __builtin_amdgcn_mfma_f32_16x16x32_bf16(a, b3, acc3, 0, 0, 0);
  }
  int crow = m0 + (l >> 4) * 4;
  int ccol = n0 + (l & 15);
#pragma unroll
  for (int r = 0; r < 4; ++r) {
    int rr = crow + r;
    if (rr < Mrows) {
      C[(size_t)rr * FD + ccol +  0] = (__bf16)acc0[r];
      C[(size_t)rr * FD + ccol + 16] = (__bf16)acc1[r];
      C[(size_t)rr * FD + ccol + 32] = (__bf16)acc2[r];
      C[(size_t)rr * FD + ccol + 48] = (__bf16)acc3[r];
    }
  }
}

// ---- edge -> node aggregation: wave per node, MLP-8, inline D ---------------

__global__ __launch_bounds__(256) void
hg_agg_e2n_bf(const __bf16* __restrict__ eWbf, const int* __restrict__ off_n,
              const int* __restrict__ mem_n, const float* __restrict__ wedge,
              const float* __restrict__ bias, __bf16* __restrict__ Outbf) {
  int node = blockIdx.x * 4 + (threadIdx.x >> 6);
  if (node >= NN) return;
  int lane = threadIdx.x & 63;
  int c = lane * 4;
  const unsigned short* eWu = (const unsigned short*)eWbf;
  int lo = off_n[node], hi = off_n[node + 1];
  float a0 = 0.f, a1 = 0.f, a2 = 0.f, a3 = 0.f;
  float dw = 0.f;
  int m = lo;
  for (; m + 8 <= hi; m += 8) {
    int i0 = mem_n[m],     i1 = mem_n[m + 1], i2 = mem_n[m + 2], i3 = mem_n[m + 3];
    int i4 = mem_n[m + 4], i5 = mem_n[m + 5], i6 = mem_n[m + 6], i7 = mem_n[m + 7];
    ushort4 v0 = *(const ushort4*)(eWu + (size_t)i0 * FD + c);
    ushort4 v1 = *(const ushort4*)(eWu + (size_t)i1 * FD + c);
    ushort4 v2 = *(const ushort4*)(eWu + (size_t)i2 * FD + c);
    ushort4 v3 = *(const ushort4*)(eWu + (size_t)i3 * FD + c);
    ushort4 v4 = *(const ushort4*)(eWu + (size_t)i4 * FD + c);
    ushort4 v5 = *(const ushort4*)(eWu + (size_t)i5 * FD + c);
    ushort4 v6 = *(const ushort4*)(eWu + (size_t)i6 * FD + c);
    ushort4 v7 = *(const ushort4*)(eWu + (size_t)i7 * FD + c);
    dw += wedge[i0] + wedge[i1] + wedge[i2] + wedge[i3]
        + wedge[i4] + wedge[i5] + wedge[i6] + wedge[i7];
    a0 += b2f(v0.x); a1 += b2f(v0.y); a2 += b2f(v0.z); a3 += b2f(v0.w);
    a0 += b2f(v1.x); a1 += b2f(v1.y); a2 += b2f(v1.z); a3 += b2f(v1.w);
    a0 += b2f(v2.x); a1 += b2f(v2.y); a2 += b2f(v2.z); a3 += b2f(v2.w);
    a0 += b2f(v3.x); a1 += b2f(v3.y); a2 += b2f(v3.z); a3 += b2f(v3.w);
    a0 += b2f(v4.x); a1 += b2f(v4.y); a2 += b2f(v4.z); a3 += b2f(v4.w);
    a0 += b2f(v5.x); a1 += b2f(v5.y); a2 += b2f(v5.z); a3 += b2f(v5.w);
    a0 += b2f(v6.x); a1 += b2f(v6.y); a2 += b2f(v6.z); a3 += b2f(v6.w);
    a0 += b2f(v7.x); a1 += b2f(v7.y); a2 += b2f(v7.z); a3 += b2f(v7.w);
  }
  for (; m < hi; ++m) {
    int i0 = mem_n[m];
    ushort4 v0 = *(const ushort4*)(eWu + (size_t)i0 * FD + c);
    dw += wedge[i0];
    a0 += b2f(v0.x); a1 += b2f(v0.y); a2 += b2f(v0.z); a3 += b2f(v0.w);
  }
  float di = (dw != 0.f) ? 1.0f / dw : 0.0f;
  float4 b4 = *(const float4*)(bias + c);
  bf16x4 o = {(__bf16)fmaf(a0, di, b4.x), (__bf16)fmaf(a1, di, b4.y),
              (__bf16)fmaf(a2, di, b4.z), (__bf16)fmaf(a3, di, b4.w)};
  *(bf16x4*)(Outbf + (size_t)node * FD + c) = o;
}

// ---- column stats over Outbf (sum, sumsq) -----------------------------------

__global__ __launch_bounds__(256) void
hg_stats(const __bf16* __restrict__ Outbf, float* __restrict__ stats) {
  int c = threadIdx.x;
  int rpb = (NN + gridDim.x - 1) / gridDim.x;
  int r0 = blockIdx.x * rpb;
  int r1 = r0 + rpb;
  if (r1 > NN) r1 = NN;
  const unsigned short* Ou = (const unsigned short*)Outbf;
  float s = 0.f, q = 0.f;
  for (int r = r0; r < r1; ++r) {
    float v = b2f(Ou[(size_t)r * FD + c]);
    s += v;
    q = fmaf(v, v, q);
  }
  atomicAdd(&stats[c], s);
  atomicAdd(&stats[FD + c], q);
}

// ---- BN finalize + final fused apply/ReLU -----------------------------------

__global__ void hg_bn_finalize(const float* __restrict__ stats, const float* __restrict__ g,
                               const float* __restrict__ be,
                               float* __restrict__ scale, float* __restrict__ shift) {
  int c = threadIdx.x;
  float mu = stats[c] * (1.0f / NN);
  float var = stats[FD + c] * (1.0f / NN) - mu * mu;
  float sc = g[c] * rsqrtf(var + EPSV);
  scale[c] = sc;
  shift[c] = fmaf(-mu, sc, be[c]);
}

__global__ void hg_apply_bf(const __bf16* __restrict__ Outbf, const float* __restrict__ scale,
                            const float* __restrict__ shift, float* __restrict__ H) {
  int idx = blockIdx.x * 256 + threadIdx.x;   // over NN*FD/8
  if (idx >= NN * FD / 8) return;
  ushort4 v0 = ((const ushort4*)Outbf)[idx * 2 + 0];
  ushort4 v1 = ((const ushort4*)Outbf)[idx * 2 + 1];
  int c = (idx & (FD / 8 - 1)) * 8;
  float4 sa = *(const float4*)(scale + c);
  float4 sb = *(const float4*)(scale + c + 4);
  float4 ha = *(const float4*)(shift + c);
  float4 hb = *(const float4*)(shift + c + 4);
  float4 o0, o1;
  o0.x = fmaxf(fmaf(b2f(v0.x), sa.x, ha.x), 0.f);
  o0.y = fmaxf(fmaf(b2f(v0.y), sa.y, ha.y), 0.f);
  o0.z = fmaxf(fmaf(b2f(v0.z), sa.z, ha.z), 0.f);
  o0.w = fmaxf(fmaf(b2f(v0.w), sa.w, ha.w), 0.f);
  o1.x = fmaxf(fmaf(b2f(v1.x), sb.x, hb.x), 0.f);
  o1.y = fmaxf(fmaf(b2f(v1.y), sb.y, hb.y), 0.f);
  o1.z = fmaxf(fmaf(b2f(v1.z), sb.z, hb.z), 0.f);
  o1.w = fmaxf(fmaf(b2f(v1.w), sb.w, hb.w), 0.f);
  ((float4*)H)[idx * 2 + 0] = o0;
  ((float4*)H)[idx * 2 + 1] = o1;
}

// ---- launch -----------------------------------------------------------------

extern "C" void kernel_launch(void* const* d_in, const int* in_sizes, int n_in,
                              void* d_out, int out_size, void* d_ws, size_t ws_size,
                              hipStream_t stream) {
  const float* x    = (const float*)d_in[0];
  const int*   hei  = (const int*)d_in[1];
  const int*   nidx = hei;               // hyperedge_index[0]
  const int*   eidx = hei + NNZV;        // hyperedge_index[1]
  const float* wedge = (const float*)d_in[2];
  const float* W1  = (const float*)d_in[3];
  const float* b1  = (const float*)d_in[4];
  const float* g1  = (const float*)d_in[5];
  const float* be1 = (const float*)d_in[6];
  const float* W2  = (const float*)d_in[7];
  const float* b2  = (const float*)d_in[8];
  const float* g2  = (const float*)d_in[9];
  const float* be2 = (const float*)d_in[10];
  float* out = (float*)d_out;

  char* base = (char*)d_ws;
  size_t cur = 0;
  auto alloc = [&](size_t bytes) -> void* {
    void* p = base + cur;
    cur += (bytes + 255) & ~(size_t)255;
    return p;
  };
  unsigned* cntc = (unsigned*)alloc((size_t)NCPY * HTC * 4);   // 17.9 MB
  unsigned short* rank_e16 = (unsigned short*)alloc((size_t)NNZV * 2);
  unsigned short* rank_n16 = (unsigned short*)alloc((size_t)NNZV * 2);
  int*   total_e = (int*)alloc(NE * 4);
  int*   total_n = (int*)alloc(NN * 4);
  int*   part  = (int*)alloc((BE + BN) * 4);
  int*   off_e = (int*)alloc((NE + 1) * 4);
  int*   off_n = (int*)alloc((NN + 1) * 4);
  int*   mem_e = (int*)alloc((size_t)NNZV * 4);
  int*   mem_n = (int*)alloc((size_t)NNZV * 4);
  __bf16* Wt1  = (__bf16*)alloc(FD * FD * 2);
  __bf16* Wt2  = (__bf16*)alloc(FD * FD * 2);
  __bf16* Xbf  = (__bf16*)alloc((size_t)NN * FD * 2);
  __bf16* Ebf  = (__bf16*)alloc((size_t)MPAD * FD * 2);
  __bf16* eWbf = (__bf16*)alloc((size_t)MPAD * FD * 2);
  __bf16* Outbf = (__bf16*)alloc((size_t)NN * FD * 2);
  float* stats = (float*)alloc(2 * FD * 4);
  float* scale1 = (float*)alloc(FD * 4);
  float* shift1 = (float*)alloc(FD * 4);
  float* scale2 = (float*)alloc(FD * 4);
  float* shift2 = (float*)alloc(FD * 4);
  if (cur > ws_size) return;

  // CSR build (no global atomics anywhere)
  hg_histlds<<<NCPY, 256, 0, stream>>>(nidx, eidx, cntc, rank_e16, rank_n16);
  hg_colreduce<<<(HTC + 255) / 256, 256, 0, stream>>>(cntc, total_e, total_n);
  hg_scan1<<<BE + BN, 256, 0, stream>>>(total_e, total_n, part);
  hg_scan2<<<1, 256, 0, stream>>>(part, off_e, off_n);
  hg_scan3<<<BE + BN, 256, 0, stream>>>(total_e, total_n, part, off_e, off_n);
  hg_scatter<<<(NNZV + 255) / 256, 256, 0, stream>>>(nidx, eidx, cntc, rank_e16, rank_n16,
                                                     off_e, off_n, mem_e, mem_n);
  hg_prep<<<FD + (NN * FD / 4 + 255) / 256, 256, 0, stream>>>(W1, W2, Wt1, Wt2, x, Xbf);

  const int N2E_BLOCKS = (NE + 3) / 4;     // wave per edge
  const int E2N_BLOCKS = (NN + 3) / 4;     // wave per node
  const dim3 GEMM_GRID(MPAD / 64, 4);

  // ---- layer 1
  hg_agg_n2e_bf<0><<<N2E_BLOCKS, 256, 0, stream>>>(Xbf, off_e, mem_e, nullptr, nullptr, Ebf);
  hg_gemm<<<GEMM_GRID, 256, 0, stream>>>(Ebf, Wt1, eWbf, NE);
  hg_agg_e2n_bf<<<E2N_BLOCKS, 256, 0, stream>>>(eWbf, off_n, mem_n, wedge, b1, Outbf);
  hipMemsetAsync(stats, 0, 2 * FD * 4, stream);
  hg_stats<<<256, 256, 0, stream>>>(Outbf, stats);
  hg_bn_finalize<<<1, FD, 0, stream>>>(stats, g1, be1, scale1, shift1);

  // ---- layer 2 (BN1+ReLU fused into the gather)
  hg_agg_n2e_bf<1><<<N2E_BLOCKS, 256, 0, stream>>>(Outbf, off_e, mem_e, scale1, shift1, Ebf);
  hg_gemm<<<GEMM_GRID, 256, 0, stream>>>(Ebf, Wt2, eWbf, NE);
  hg_agg_e2n_bf<<<E2N_BLOCKS, 256, 0, stream>>>(eWbf, off_n, mem_n, wedge, b2, Outbf);
  hipMemsetAsync(stats, 0, 2 * FD * 4, stream);
  hg_stats<<<256, 256, 0, stream>>>(Outbf, stats);
  hg_bn_finalize<<<1, FD, 0, stream>>>(stats, g2, be2, scale2, shift2);
  hg_apply_bf<<<(NN * FD / 8 + 255) / 256, 256, 0, stream>>>(Outbf, scale2, shift2, out);
}